// Round 4
// baseline (349.256 us; speedup 1.0000x reference)
//
#include <hip/hip_runtime.h>

// ---------------------------------------------------------------------------
// MatryoshkaAttention on MI355X (gfx950), bf16 MFMA pipeline. Round 10.
//
// Changes vs R9 (k_gemm1 only):
//  - STATIC LDS buffers (8 named arrays, 128 KiB) + 4x-unrolled K-loop with
//    compile-time buffer names: lets LLVM's waitcnt pass disambiguate
//    global_load_lds -> ds_read hazards per LDS object instead of inserting
//    conservative drains for the runtime-indexed Ls[b][..] of R9 (theory for
//    R9's unchanged 96.5 us / 29% MfmaUtil: ~2800 cy/iter latency exposure).
//  - Prefetch depth 3 (tiles t+1,t+2 landed/in-flight, t+3 issuing);
//    boundary s_waitcnt vmcnt(8) per tile, never 0 mid-loop.
//  - Grid exactly 256 blocks: 240 long (Keff=2048) + 16 combo blocks that
//    sweep the three short Q-columns (Keff 256,1024,1024) sequentially.
// ---------------------------------------------------------------------------

typedef short bf16x8 __attribute__((ext_vector_type(8)));
typedef float floatx4 __attribute__((ext_vector_type(4)));

__device__ __forceinline__ unsigned short f2bf(float f) {
  unsigned u = __builtin_bit_cast(unsigned, f);
  u += 0x7fffu + ((u >> 16) & 1u);           // RNE
  return (unsigned short)(u >> 16);
}

__device__ __forceinline__ void gload_lds16(const unsigned short* g, unsigned short* l) {
  __builtin_amdgcn_global_load_lds((const __attribute__((address_space(1))) unsigned int*)g,
                                   (__attribute__((address_space(3))) unsigned int*)l, 16, 0, 0);
}

// ---------------- 1. fused prep: cvt_x | pack_qkv(+corr) | pack_o ----------
// blocks [0,8192): x->bf16 ; [8192,17408): W_QKV pack ; [17408,20480): W_O.
__global__ __launch_bounds__(256) void k_prep(
    const float* __restrict__ x, unsigned short* __restrict__ X16,
    const float* __restrict__ WQ, const float* __restrict__ WK, const float* __restrict__ WV,
    const float* __restrict__ FK0, const float* __restrict__ PK0,
    const float* __restrict__ FV0, const float* __restrict__ PV0,
    const float* __restrict__ FK1, const float* __restrict__ PK1,
    const float* __restrict__ FV1, const float* __restrict__ PV1,
    unsigned short* __restrict__ WTQKV,
    const float* __restrict__ WO, unsigned short* __restrict__ WTO) {
  __shared__ float tile[32][33];
  __shared__ float Fs[32][9];
  __shared__ float Ps[8][32];
  const int bid = blockIdx.x;
  const int tid = threadIdx.x;
  if (bid < 8192) {                       // ---- x -> bf16 (float4 per thread)
    int i = bid * 256 + tid;
    float4 v = ((const float4*)x)[i];
    union { unsigned short u[4]; uint2 v2; } o;
    o.u[0] = f2bf(v.x); o.u[1] = f2bf(v.y); o.u[2] = f2bf(v.z); o.u[3] = f2bf(v.w);
    ((uint2*)X16)[i] = o.v2;
    return;
  }
  const int tx = tid & 31, ty = tid >> 5;
  if (bid < 17408) {                      // ---- W_QKV transpose + corrections
    int t = bid - 8192;
    int k0 = (t & 63) * 32, n0 = (t >> 6) * 32;
    const float* src; int nboff;
    if (n0 < 1536)      { src = WQ; nboff = n0; }
    else if (n0 < 3072) { src = WK; nboff = n0 - 1536; }
    else                { src = WV; nboff = n0 - 3072; }
#pragma unroll
    for (int j = 0; j < 4; ++j) {
      int kk = ty + j * 8;
      tile[kk][tx] = src[(size_t)(k0 + kk) * 1536 + nboff + tx];
    }
    int corrsel = 0; const float* Fsrc = nullptr; const float* Psrc = nullptr;
    int h = 0, d0 = 0, fs = 0, koff = 0;
    if (n0 >= 1536) {
      bool isK = (n0 < 3072);
      int np0 = isK ? (n0 - 1536) : (n0 - 3072);
      if (np0 < 256) {
        if (k0 >= 256) { corrsel = 1; Fsrc = isK ? FK0 : FV0; Psrc = isK ? PK0 : PV0;
                         h = np0 >> 6; d0 = np0 & 63; fs = 32; koff = k0 - 256; }
      } else if (np0 < 768) {
        if (k0 >= 1024) { corrsel = 1; Fsrc = isK ? FK1 : FV1; Psrc = isK ? PK1 : PV1;
                          h = (np0 - 256) >> 6; d0 = (np0 - 256) & 63; fs = 64; koff = k0 - 1024; }
      }
    }
    if (corrsel) {
      Fs[tid >> 3][tid & 7] = Fsrc[(size_t)(koff + (tid >> 3)) * fs + h * 8 + (tid & 7)];
      Ps[tid >> 5][tid & 31] = Psrc[h * 512 + (tid >> 5) * 64 + d0 + (tid & 31)];
    }
    __syncthreads();
#pragma unroll
    for (int j = 0; j < 4; ++j) {
      int nn = ty + j * 8;
      float v = tile[tx][nn];
      if (corrsel) {
        float c = 0.f;
#pragma unroll
        for (int r = 0; r < 8; ++r) c += Fs[tx][r] * Ps[r][nn];
        v += c;
      }
      WTQKV[(size_t)(n0 + nn) * 2048 + k0 + tx] = f2bf(v);
    }
  } else {                                // ---- W_O transpose
    int t = bid - 17408;
    int k0 = (t % 48) * 32, n0 = (t / 48) * 32;
#pragma unroll
    for (int j = 0; j < 4; ++j)
      tile[ty + j * 8][tx] = WO[(size_t)(k0 + ty + j * 8) * 2048 + n0 + tx];
    __syncthreads();
#pragma unroll
    for (int j = 0; j < 4; ++j)
      WTO[(size_t)(n0 + ty + j * 8) * 1536 + k0 + tx] = f2bf(tile[tx][ty + j * 8]);
  }
}

// ---------------- 4. QKV GEMM: 256x256, BK=32, 4 static buffers, depth-3 ----
// A = X16 [4096][2048] bf16; Bt = WTQKV [4608][2048]; C bf16 [4096][4608].
// 512 threads = 8 waves (2M x 4N); per-wave C = 128x64 = 8x4 fp32x4 frags.
// LDS per 256x32 tile: 128-byte lines (2 rows x 4 k-groups of 8 bf16),
// slot = ((row&1)*4 + kgroup) ^ (line&7); staging pre-swizzles the GLOBAL
// source per lane, LDS dest stays linear (bijective, conflict-free).
// Pipeline: compute tile t (buf t&3) | t+1,t+2 landed/in-flight | stage t+3.
// Boundary per tile: s_waitcnt vmcnt(8) then barrier (retires exactly t+1).
__device__ __forceinline__ int lds_off(int row, int kq) {
  int L = row >> 1;
  return L * 64 + ((((row & 1) << 2) | kq) ^ (L & 7)) * 8;
}

#define VM8 asm volatile("s_waitcnt vmcnt(8)" ::: "memory")
#define VM4 asm volatile("s_waitcnt vmcnt(4)" ::: "memory")
#define VM0 asm volatile("s_waitcnt vmcnt(0)" ::: "memory")
#define BAR __builtin_amdgcn_s_barrier()

#define TILE_STEP(AP, BP, AQ, BQ, STG, K3, FIN)                                \
  do {                                                                         \
    bf16x8 bfr[4], af[4];                                                      \
    _Pragma("unroll")                                                          \
    for (int ni = 0; ni < 4; ++ni) bfr[ni] = *(const bf16x8*)((BP) + boff[ni]);\
    _Pragma("unroll")                                                          \
    for (int mi = 0; mi < 4; ++mi) af[mi] = *(const bf16x8*)((AP) + aoff[mi]); \
    if (STG) {                                                                 \
      gload_lds16(gA + (K3), (AQ) + wave * 512);                               \
      gload_lds16(gA + 128 * 2048 + (K3), (AQ) + wave * 512 + 4096);           \
      gload_lds16(gB + (K3), (BQ) + wave * 512);                               \
      gload_lds16(gB + 128 * 2048 + (K3), (BQ) + wave * 512 + 4096);           \
    }                                                                          \
    BAR;                                                                       \
    __builtin_amdgcn_s_setprio(1);                                             \
    _Pragma("unroll")                                                          \
    for (int mi = 0; mi < 4; ++mi)                                             \
      _Pragma("unroll")                                                        \
      for (int ni = 0; ni < 4; ++ni)                                           \
        acc[mi][ni] = __builtin_amdgcn_mfma_f32_16x16x32_bf16(af[mi], bfr[ni], acc[mi][ni], 0, 0, 0); \
    __builtin_amdgcn_s_setprio(0);                                             \
    BAR;                                                                       \
    _Pragma("unroll")                                                          \
    for (int mi = 0; mi < 4; ++mi) af[mi] = *(const bf16x8*)((AP) + aoff[4 + mi]); \
    BAR;                                                                       \
    __builtin_amdgcn_s_setprio(1);                                             \
    _Pragma("unroll")                                                          \
    for (int mi = 0; mi < 4; ++mi)                                             \
      _Pragma("unroll")                                                        \
      for (int ni = 0; ni < 4; ++ni)                                           \
        acc[4 + mi][ni] = __builtin_amdgcn_mfma_f32_16x16x32_bf16(af[mi], bfr[ni], acc[4 + mi][ni], 0, 0, 0); \
    __builtin_amdgcn_s_setprio(0);                                             \
    FIN;                                                                       \
  } while (0)

__global__ __launch_bounds__(512) void k_gemm1(const unsigned short* __restrict__ A,
                                               const unsigned short* __restrict__ Bt,
                                               unsigned short* __restrict__ C) {
  __shared__ unsigned short As0[8192], As1[8192], As2[8192], As3[8192];
  __shared__ unsigned short Bs0[8192], Bs1[8192], Bs2[8192], Bs3[8192];
  const int tid = threadIdx.x;
  const int wave = tid >> 6, lane = tid & 63;
  const int qd = lane >> 4, ln = lane & 15;
  const int wr = wave >> 2, wc = wave & 3;
  const int idx = blockIdx.x;
  // 256 blocks exactly: 240 long + 16 combo (3 short Q-columns each).
  int by, nsub, bns[3], kfs[3];
  if (idx < 240) {
    by = idx / 15; nsub = 1;
    bns[0] = (3 + idx % 15) * 256; kfs[0] = 2048;
    bns[1] = bns[2] = 0; kfs[1] = kfs[2] = 0;
  } else {
    by = idx - 240; nsub = 3;
    bns[0] = 0;   kfs[0] = 256;
    bns[1] = 256; kfs[1] = 1024;
    bns[2] = 512; kfs[2] = 1024;
  }
  const int bm = by * 256;

  // staging source map (inverse of LDS swizzle): thread -> (line, slot)
  const int Lr = tid >> 3, sl = tid & 7;
  const int gg = sl ^ (Lr & 7);
  const int srow = 2 * Lr + (gg >> 2);        // 0..127 (second gload adds 128)
  const int skg = gg & 3;
  const unsigned short* gA = A + (size_t)(bm + srow) * 2048 + skg * 8;

  // ds_read fragment offsets (loop-invariant)
  int aoff[8], boff[4];
#pragma unroll
  for (int mi = 0; mi < 8; ++mi) aoff[mi] = lds_off(wr * 128 + mi * 16 + ln, qd);
#pragma unroll
  for (int ni = 0; ni < 4; ++ni) boff[ni] = lds_off(wc * 64 + ni * 16 + ln, qd);

  for (int s = 0; s < nsub; ++s) {
    const int bn = bns[s];
    const int NT = kfs[s] >> 5;               // 64 / 32 / 8 — all multiples of 4
    const unsigned short* gB = Bt + (size_t)(bn + srow) * 2048 + skg * 8;
    floatx4 acc[8][4];
#pragma unroll
    for (int i = 0; i < 8; ++i)
#pragma unroll
      for (int j = 0; j < 4; ++j) acc[i][j] = (floatx4){0.f, 0.f, 0.f, 0.f};

    // ---- prologue: tiles 0,1,2 -> bufs 0,1,2 (FIFO issue order)
    gload_lds16(gA, As0 + wave * 512);
    gload_lds16(gA + 128 * 2048, As0 + wave * 512 + 4096);
    gload_lds16(gB, Bs0 + wave * 512);
    gload_lds16(gB + 128 * 2048, Bs0 + wave * 512 + 4096);
    gload_lds16(gA + 32, As1 + wave * 512);
    gload_lds16(gA + 128 * 2048 + 32, As1 + wave * 512 + 4096);
    gload_lds16(gB + 32, Bs1 + wave * 512);
    gload_lds16(gB + 128 * 2048 + 32, Bs1 + wave * 512 + 4096);
    gload_lds16(gA + 64, As2 + wave * 512);
    gload_lds16(gA + 128 * 2048 + 64, As2 + wave * 512 + 4096);
    gload_lds16(gB + 64, Bs2 + wave * 512);
    gload_lds16(gB + 128 * 2048 + 64, Bs2 + wave * 512 + 4096);
    VM8;                                      // tile 0 landed; 1,2 in flight
    BAR;

    for (int t4 = 0; t4 < NT; t4 += 4) {
      const bool more = (t4 + 4) < NT;
      TILE_STEP(As0, Bs0, As3, Bs3, true, (t4 + 3) << 5, VM8; BAR);
      TILE_STEP(As1, Bs1, As0, Bs0, more, (t4 + 4) << 5,
                if (more) { VM8; } else { VM4; } BAR);
      TILE_STEP(As2, Bs2, As1, Bs1, more, (t4 + 5) << 5,
                if (more) { VM8; } else { VM0; } BAR);
      TILE_STEP(As3, Bs3, As2, Bs2, more, (t4 + 6) << 5,
                if (more) { VM8; BAR; });
    }

    // ---- epilogue for this sub-column
#pragma unroll
    for (int mi = 0; mi < 8; ++mi)
#pragma unroll
      for (int r = 0; r < 4; ++r) {
        size_t row = (size_t)(bm + wr * 128 + mi * 16 + qd * 4 + r);
#pragma unroll
        for (int ni = 0; ni < 4; ++ni) {
          int col = bn + wc * 64 + ni * 16 + ln;
          C[row * 4608 + col] = f2bf(acc[mi][ni][r]);
        }
      }
  }
}

// ---------------- 6. out GEMM BK=64, Keff per column block, LPT dispatch ----
// MODE 1: out (N=2048, 16 cols: long bx8..15, mid bx2..7, short bx0..1)
template <bool OUT_BF16, int MODE>
__global__ __launch_bounds__(256) void k_gemm_bt(const unsigned short* __restrict__ A,
                                                 const unsigned short* __restrict__ Bt,
                                                 void* __restrict__ C, int M, int N, int K) {
  __shared__ unsigned short As[128 * 64];
  __shared__ unsigned short Bs[128 * 64];
  const int tid = threadIdx.x;
  const int wave = tid >> 6, lane = tid & 63;
  const int qd = lane >> 4, ln = lane & 15;
  int idx = blockIdx.x, bx, by;
  if (MODE == 0) {
    if (idx < 960)       { bx = 6 + idx % 30; by = idx / 30; }
    else if (idx < 1088) { int t = idx - 960; bx = 2 + (t & 3); by = t >> 2; }
    else                 { int t = idx - 1088; bx = t & 1; by = t >> 1; }
  } else {
    if (idx < 256)       { bx = 8 + (idx & 7); by = idx >> 3; }
    else if (idx < 448)  { int t = idx - 256; bx = 2 + t % 6; by = t / 6; }
    else                 { int t = idx - 448; bx = t & 1; by = t >> 1; }
  }
  const int bm = by * 128, bn = bx * 128;
  const int wr = wave >> 1, wc = wave & 1;
  int Keff;
  if (MODE == 0) Keff = (bn < 256) ? 256 : (bn < 768 ? 1024 : 2048);
  else           Keff = (bn < 256) ? 256 : (bn < 1024 ? 768 : 1536);
  floatx4 acc[4][4];
#pragma unroll
  for (int i = 0; i < 4; ++i)
#pragma unroll
    for (int j = 0; j < 4; ++j) acc[i][j] = (floatx4){0.f, 0.f, 0.f, 0.f};
  const int rl = lane >> 3;                        // row mod 8
  const int sg = (lane & 7) ^ rl;                  // swizzled source group
  const unsigned short* gA = A + (size_t)(bm + wave * 32 + rl) * K + sg * 8;
  const unsigned short* gB = Bt + (size_t)(bn + wave * 32 + rl) * K + sg * 8;
  unsigned short* lA = As + wave * 2048;
  unsigned short* lB = Bs + wave * 2048;
  const int l7 = ln & 7;
  for (int k0 = 0; k0 < Keff; k0 += 64) {
    __syncthreads();
#pragma unroll
    for (int i = 0; i < 4; ++i) {
      gload_lds16(gA + (size_t)8 * i * K + k0, lA + i * 512);
      gload_lds16(gB + (size_t)8 * i * K + k0, lB + i * 512);
    }
    __syncthreads();
#pragma unroll
    for (int h = 0; h < 2; ++h) {
      bf16x8 af[4], bfr[4];
#pragma unroll
      for (int mi = 0; mi < 4; ++mi)
        af[mi] = *(const bf16x8*)(As + (wr * 64 + mi * 16 + ln) * 64 + ((h * 4 + qd) ^ l7) * 8);
#pragma unroll
      for (int ni = 0; ni < 4; ++ni)
        bfr[ni] = *(const bf16x8*)(Bs + (wc * 64 + ni * 16 + ln) * 64 + ((h * 4 + qd) ^ l7) * 8);
#pragma unroll
      for (int mi = 0; mi < 4; ++mi)
#pragma unroll
        for (int ni = 0; ni < 4; ++ni)
          acc[mi][ni] = __builtin_amdgcn_mfma_f32_16x16x32_bf16(af[mi], bfr[ni], acc[mi][ni], 0, 0, 0);
    }
  }
#pragma unroll
  for (int mi = 0; mi < 4; ++mi)
#pragma unroll
    for (int r = 0; r < 4; ++r) {
      int row = bm + wr * 64 + mi * 16 + qd * 4 + r;
#pragma unroll
      for (int ni = 0; ni < 4; ++ni) {
        int col = bn + wc * 64 + ni * 16 + ln;
        if (OUT_BF16)
          ((unsigned short*)C)[(size_t)row * N + col] = f2bf(acc[mi][ni][r]);
        else
          ((float*)C)[(size_t)row * N + col] = acc[mi][ni][r];
      }
    }
}

// ---------------- 4b. V transpose: VT[b][d(1536)][T] from QKV cols 3072+ ----
__global__ void k_transpose_v(const unsigned short* __restrict__ QKV,
                              unsigned short* __restrict__ VT) {
  __shared__ unsigned short t[64 * 65];
  const int tt = blockIdx.x * 64, dt = blockIdx.y * 64, b = blockIdx.z;
  const int tid = threadIdx.x;
  const int r = tid >> 3, c0 = (tid & 7) * 8;
#pragma unroll
  for (int i = 0; i < 2; ++i) {
    int tok = r + i * 32;
    union { uint4 v; unsigned short u[8]; } vv;
    vv.v = *(const uint4*)(QKV + (size_t)(b * 1024 + tt + tok) * 4608 + 3072 + dt + c0);
#pragma unroll
    for (int j = 0; j < 8; ++j) t[tok * 65 + c0 + j] = vv.u[j];
  }
  __syncthreads();
#pragma unroll
  for (int i = 0; i < 2; ++i) {
    int d = r + i * 32;
    union { uint4 v; unsigned short u[8]; } vv;
#pragma unroll
    for (int j = 0; j < 8; ++j) vv.u[j] = t[(c0 + j) * 65 + d];
    *(uint4*)(VT + ((size_t)b * 1536 + dt + d) * 1024 + tt + c0) = vv.v;
  }
}

// ---------------- 5. causal flash attention, 128q x 128k tiles --------------
// grid (8 qtiles [reversed], 24 heads, 4 batch), block 256 = 4 waves.
// Wave: 2 q-frags (16 rows, 64 apart). No-max exp2 softmax, deferred l.
// Diagonal tile: frag0 computes keys [0,64) only; frag1 masks keys >= 64.
#define LDP 136
__global__ __launch_bounds__(256) void k_attn(const unsigned short* __restrict__ QKV,
                                              const unsigned short* __restrict__ VT,
                                              unsigned short* __restrict__ Oout) {
  __shared__ unsigned short Ks[128 * 64];     // [key][d], 8-grp XOR swizzle
  __shared__ unsigned short VTs[64 * 128];    // [d][key], 16-grp XOR swizzle
  __shared__ unsigned short Pl[4][16 * LDP];  // wave-private P staging
  const int tid = threadIdx.x;
  const int wave = tid >> 6, lane = tid & 63;
  const int qd = lane >> 4, ln = lane & 15;
  const int qb = (int)gridDim.x - 1 - (int)blockIdx.x;   // big blocks first
  const int gh = blockIdx.y, b = blockIdx.z;
  const int T = 1024, LD = 4608;
  const size_t rowbase = (size_t)b * T * LD;
  const int qcol = 64 * gh, kcol = 1536 + 64 * gh;
  const unsigned short* VTg = VT + ((size_t)b * 1536 + 64 * gh) * 1024;
  const float SCALE = 0.18033688f;  // 1/sqrt(64) * log2(e)
  const int q0 = qb * 128 + wave * 16;       // frag j adds j*64

  bf16x8 aq[2][2];
#pragma unroll
  for (int j = 0; j < 2; ++j) {
    const unsigned short* qp = QKV + rowbase + (size_t)(q0 + j * 64 + ln) * LD + qcol;
    aq[j][0] = *(const bf16x8*)(qp + qd * 8);
    aq[j][1] = *(const bf16x8*)(qp + 32 + qd * 8);
  }
  floatx4 Oacc[2][4];
#pragma unroll
  for (int j = 0; j < 2; ++j)
#pragma unroll
    for (int i = 0; i < 4; ++i) Oacc[j][i] = (floatx4){0.f, 0.f, 0.f, 0.f};
  float l_lane[2] = {0.f, 0.f};

  // K staging: wave stages rows [wave*32, +32) (4 gloads x 8 rows)
  const int rk = lane >> 3;                   // 0..7
  const int gk = ((lane & 7) ^ rk) * 8;       // swizzled source group (8-grp)
  const unsigned short* gK = QKV + rowbase + (size_t)(wave * 32 + rk) * LD + kcol + gk;
  unsigned short* lK = Ks + wave * 32 * 64;
  // VT staging: wave stages d-rows [wave*16, +16) (4 gloads x 4 rows x 128 c)
  const int rv = lane >> 4;                   // 0..3
  const int cv = lane & 15;
  unsigned short* lV = VTs + wave * 16 * 128;
  const unsigned short* gVrow[4];
  int gvcol[4];
#pragma unroll
  for (int i = 0; i < 4; ++i) {
    int d = wave * 16 + 4 * i + rv;
    gVrow[i] = VTg + (size_t)d * 1024;
    gvcol[i] = (cv ^ (4 * i + rv)) * 8;       // 16-grp swizzle by d&15
  }
  const int l7 = ln & 7;

  for (int jt = 0; jt <= qb; ++jt) {
    const int jk = jt * 128;
    const bool diag = (jt == qb);
    __syncthreads();
#pragma unroll
    for (int i = 0; i < 4; ++i) {
      gload_lds16(gK + (size_t)(jk + 8 * i) * LD, lK + i * 512);
      gload_lds16(gVrow[i] + jk + gvcol[i], lV + i * 512);
    }
    __syncthreads();

#pragma unroll
    for (int j = 0; j < 2; ++j) {
      const bool dj0 = diag && (j == 0);
      const int hmax = dj0 ? 4 : 8;
      // S^T = K Q^T : A = K[key][d] (frag h = keys h*16..+16), B = Q
      floatx4 Sc[8];
#pragma unroll
      for (int h = 0; h < 8; ++h) {
        if (h >= hmax) continue;
        Sc[h] = (floatx4){0.f, 0.f, 0.f, 0.f};
        bf16x8 a0 = *(const bf16x8*)(Ks + (h * 16 + ln) * 64 + (qd ^ l7) * 8);
        bf16x8 a1 = *(const bf16x8*)(Ks + (h * 16 + ln) * 64 + ((4 + qd) ^ l7) * 8);
        Sc[h] = __builtin_amdgcn_mfma_f32_16x16x32_bf16(a0, aq[j][0], Sc[h], 0, 0, 0);
        Sc[h] = __builtin_amdgcn_mfma_f32_16x16x32_bf16(a1, aq[j][1], Sc[h], 0, 0, 0);
      }
      const int qrow = q0 + j * 64 + ln;
      unsigned short* pw = Pl[wave];
#pragma unroll
      for (int h = 0; h < 8; ++h) {
        if (h >= hmax) continue;
        union { unsigned short u[4]; uint2 v; } pk;
#pragma unroll
        for (int r = 0; r < 4; ++r) {
          float v = fminf(Sc[h][r] * SCALE, 80.f);
          float p = __builtin_amdgcn_exp2f(v);
          if (diag && (j == 0 || h >= 4)) {
            int key = jk + h * 16 + qd * 4 + r;
            if (key > qrow) p = 0.f;
          }
          l_lane[j] += p;
          pk.u[r] = f2bf(p);
        }
        *(uint2*)(pw + ln * LDP + h * 16 + qd * 4) = pk.v;
      }
      __asm__ volatile("s_waitcnt lgkmcnt(0)" ::: "memory");
      const int smax = dj0 ? 2 : 4;
      bf16x8 pa[4];
#pragma unroll
      for (int s = 0; s < 4; ++s) {
        if (s >= smax) continue;
        pa[s] = *(const bf16x8*)(pw + ln * LDP + s * 32 + qd * 8);
      }
#pragma unroll
      for (int nc = 0; nc < 4; ++nc) {
        const int d = nc * 16 + ln;
#pragma unroll
        for (int s = 0; s < 4; ++s) {
          if (s >= smax) continue;
          bf16x8 bv = *(const bf16x8*)(VTs + d * 128 + (((s * 4 + qd) ^ ln) & 15) * 8);
          Oacc[j][nc] = __builtin_amdgcn_mfma_f32_16x16x32_bf16(pa[s], bv, Oacc[j][nc], 0, 0, 0);
        }
      }
    }
  }
  // l: sum the 4 qd-groups per ln, then normalize + store
#pragma unroll
  for (int j = 0; j < 2; ++j) {
    float l = l_lane[j];
    l += __shfl_xor(l, 16, 64);
    l += __shfl_xor(l, 32, 64);
#pragma unroll
    for (int r = 0; r < 4; ++r) {
      float inv = 1.0f / __shfl(l, qd * 4 + r, 64);
      size_t row = (size_t)b * T + q0 + j * 64 + qd * 4 + r;
#pragma unroll
      for (int nc = 0; nc < 4; ++nc)
        Oout[row * 1536 + 64 * gh + nc * 16 + ln] = f2bf(Oacc[j][nc][r] * inv);
    }
  }
}

// ---------------------------------------------------------------------------
extern "C" void kernel_launch(void* const* d_in, const int* in_sizes, int n_in,
                              void* d_out, int out_size, void* d_ws, size_t ws_size,
                              hipStream_t stream) {
  (void)in_sizes; (void)n_in; (void)out_size; (void)ws_size;
  const float* x   = (const float*)d_in[0];
  const float* WQ  = (const float*)d_in[1];
  const float* WK  = (const float*)d_in[2];
  const float* WV  = (const float*)d_in[3];
  const float* WO  = (const float*)d_in[4];
  const float* FK0 = (const float*)d_in[5];
  const float* PK0 = (const float*)d_in[6];
  const float* FV0 = (const float*)d_in[7];
  const float* PV0 = (const float*)d_in[8];
  const float* FK1 = (const float*)d_in[9];
  const float* PK1 = (const float*)d_in[10];
  const float* FV1 = (const float*)d_in[11];
  const float* PV1 = (const float*)d_in[12];

  char* ws = (char*)d_ws;
  unsigned short* X16   = (unsigned short*)(ws + 0);          // 16 MB (dead after GEMM1)
  unsigned short* VTb   = X16;                                 // VT aliases X16
  unsigned short* WTQKV = (unsigned short*)(ws + 16777216);   // 18 MB
  unsigned short* QKV   = (unsigned short*)(ws + 35651584);   // 36 MB
  unsigned short* ATT   = (unsigned short*)(ws + 73400320);   // 12 MB
  unsigned short* WTO   = (unsigned short*)(ws + 85983232);   //  6 MB

  k_prep<<<20480, 256, 0, stream>>>(x, X16, WQ, WK, WV,
                                    FK0, PK0, FV0, PV0, FK1, PK1, FV1, PV1,
                                    WTQKV, WO, WTO);
  k_gemm1<<<256, 512, 0, stream>>>(X16, WTQKV, QKV);
  k_transpose_v<<<dim3(16, 24, 4), 256, 0, stream>>>(QKV, VTb);
  k_attn<<<dim3(8, 24, 4), 256, 0, stream>>>(QKV, VTb, ATT);
  k_gemm_bt<false, 1><<<512, 256, 0, stream>>>(ATT, WTO, d_out, 4096, 2048, 1536);
}

// Round 5
// 335.182 us; speedup vs baseline: 1.0420x; 1.0420x over previous
//
#include <hip/hip_runtime.h>

// ---------------------------------------------------------------------------
// MatryoshkaAttention on MI355X (gfx950), bf16 MFMA pipeline. Round 11.
//
// Changes vs R10:
//  - k_gemm1 reverted to R9 exact (runtime-indexed triple buffer, 96 VGPR).
//    R10's static 4x-unroll spilled (VGPR 128, WRITE_SIZE doubled = scratch).
//  - k_gemm2 (new, replaces k_gemm_bt<MODE 1>): 64x128 tiles, BK=32,
//    1024 blocks -> 4 blocks/CU residency (36 KiB LDS), triple-buffered
//    counted-vmcnt pipeline (vmcnt(3) boundary, never 0 mid-loop), static
//    buffer names via 3-step groups. gemm2 is latency-bound (L2-resident
//    inputs, 190 TF at 2 blocks/CU); TLP 2->4 + counted waits is the lever.
//    Tier-0 K=256 padded to 288 (block-UT mask zeroes cols 256+ -> harmless).
// ---------------------------------------------------------------------------

typedef short bf16x8 __attribute__((ext_vector_type(8)));
typedef float floatx4 __attribute__((ext_vector_type(4)));

__device__ __forceinline__ unsigned short f2bf(float f) {
  unsigned u = __builtin_bit_cast(unsigned, f);
  u += 0x7fffu + ((u >> 16) & 1u);           // RNE
  return (unsigned short)(u >> 16);
}

__device__ __forceinline__ void gload_lds16(const unsigned short* g, unsigned short* l) {
  __builtin_amdgcn_global_load_lds((const __attribute__((address_space(1))) unsigned int*)g,
                                   (__attribute__((address_space(3))) unsigned int*)l, 16, 0, 0);
}

// ---------------- 1. fused prep: cvt_x | pack_qkv(+corr) | pack_o ----------
// blocks [0,8192): x->bf16 ; [8192,17408): W_QKV pack ; [17408,20480): W_O.
__global__ __launch_bounds__(256) void k_prep(
    const float* __restrict__ x, unsigned short* __restrict__ X16,
    const float* __restrict__ WQ, const float* __restrict__ WK, const float* __restrict__ WV,
    const float* __restrict__ FK0, const float* __restrict__ PK0,
    const float* __restrict__ FV0, const float* __restrict__ PV0,
    const float* __restrict__ FK1, const float* __restrict__ PK1,
    const float* __restrict__ FV1, const float* __restrict__ PV1,
    unsigned short* __restrict__ WTQKV,
    const float* __restrict__ WO, unsigned short* __restrict__ WTO) {
  __shared__ float tile[32][33];
  __shared__ float Fs[32][9];
  __shared__ float Ps[8][32];
  const int bid = blockIdx.x;
  const int tid = threadIdx.x;
  if (bid < 8192) {                       // ---- x -> bf16 (float4 per thread)
    int i = bid * 256 + tid;
    float4 v = ((const float4*)x)[i];
    union { unsigned short u[4]; uint2 v2; } o;
    o.u[0] = f2bf(v.x); o.u[1] = f2bf(v.y); o.u[2] = f2bf(v.z); o.u[3] = f2bf(v.w);
    ((uint2*)X16)[i] = o.v2;
    return;
  }
  const int tx = tid & 31, ty = tid >> 5;
  if (bid < 17408) {                      // ---- W_QKV transpose + corrections
    int t = bid - 8192;
    int k0 = (t & 63) * 32, n0 = (t >> 6) * 32;
    const float* src; int nboff;
    if (n0 < 1536)      { src = WQ; nboff = n0; }
    else if (n0 < 3072) { src = WK; nboff = n0 - 1536; }
    else                { src = WV; nboff = n0 - 3072; }
#pragma unroll
    for (int j = 0; j < 4; ++j) {
      int kk = ty + j * 8;
      tile[kk][tx] = src[(size_t)(k0 + kk) * 1536 + nboff + tx];
    }
    int corrsel = 0; const float* Fsrc = nullptr; const float* Psrc = nullptr;
    int h = 0, d0 = 0, fs = 0, koff = 0;
    if (n0 >= 1536) {
      bool isK = (n0 < 3072);
      int np0 = isK ? (n0 - 1536) : (n0 - 3072);
      if (np0 < 256) {
        if (k0 >= 256) { corrsel = 1; Fsrc = isK ? FK0 : FV0; Psrc = isK ? PK0 : PV0;
                         h = np0 >> 6; d0 = np0 & 63; fs = 32; koff = k0 - 256; }
      } else if (np0 < 768) {
        if (k0 >= 1024) { corrsel = 1; Fsrc = isK ? FK1 : FV1; Psrc = isK ? PK1 : PV1;
                          h = (np0 - 256) >> 6; d0 = (np0 - 256) & 63; fs = 64; koff = k0 - 1024; }
      }
    }
    if (corrsel) {
      Fs[tid >> 3][tid & 7] = Fsrc[(size_t)(koff + (tid >> 3)) * fs + h * 8 + (tid & 7)];
      Ps[tid >> 5][tid & 31] = Psrc[h * 512 + (tid >> 5) * 64 + d0 + (tid & 31)];
    }
    __syncthreads();
#pragma unroll
    for (int j = 0; j < 4; ++j) {
      int nn = ty + j * 8;
      float v = tile[tx][nn];
      if (corrsel) {
        float c = 0.f;
#pragma unroll
        for (int r = 0; r < 8; ++r) c += Fs[tx][r] * Ps[r][nn];
        v += c;
      }
      WTQKV[(size_t)(n0 + nn) * 2048 + k0 + tx] = f2bf(v);
    }
  } else {                                // ---- W_O transpose
    int t = bid - 17408;
    int k0 = (t % 48) * 32, n0 = (t / 48) * 32;
#pragma unroll
    for (int j = 0; j < 4; ++j)
      tile[ty + j * 8][tx] = WO[(size_t)(k0 + ty + j * 8) * 2048 + n0 + tx];
    __syncthreads();
#pragma unroll
    for (int j = 0; j < 4; ++j)
      WTO[(size_t)(n0 + ty + j * 8) * 1536 + k0 + tx] = f2bf(tile[tx][ty + j * 8]);
  }
}

// ---------------- 4. QKV GEMM: 256x256 tile, BK=32, triple-buffer pipeline --
// (R9 exact.) A = X16 [4096][2048]; Bt = WTQKV [4608][2048]; C bf16 [4096][4608].
__device__ __forceinline__ int lds_off(int row, int kq) {
  int L = row >> 1;
  return L * 64 + ((((row & 1) << 2) | kq) ^ (L & 7)) * 8;
}

__global__ __launch_bounds__(512) void k_gemm1(const unsigned short* __restrict__ A,
                                               const unsigned short* __restrict__ Bt,
                                               unsigned short* __restrict__ C) {
  __shared__ unsigned short Ls[3][2][8192];   // [buf][A=0/B=1][256*32]
  const int tid = threadIdx.x;
  const int wave = tid >> 6, lane = tid & 63;
  const int qd = lane >> 4, ln = lane & 15;
  const int wr = wave >> 2, wc = wave & 3;
  // LPT dispatch: 240 long (Keff=2048) first, then 32 mid (1024), 16 short (256)
  int idx = blockIdx.x, bx, by, Keff;
  if (idx < 240)      { bx = 3 + idx % 15; by = idx / 15; Keff = 2048; }
  else if (idx < 272) { int t2 = idx - 240; bx = 1 + (t2 & 1); by = t2 >> 1; Keff = 1024; }
  else                { bx = 0; by = idx - 272; Keff = 256; }
  const int bm = by * 256, bn = bx * 256;
  const int NT = Keff >> 5;

  // staging source map (inverse of LDS swizzle): thread -> (line, slot)
  const int Lr = tid >> 3, sl = tid & 7;
  const int gg = sl ^ (Lr & 7);
  const int srow = 2 * Lr + (gg >> 2);        // 0..127 (load1 adds 128)
  const int skg = gg & 3;
  const unsigned short* gA = A + (size_t)(bm + srow) * 2048 + skg * 8;
  const unsigned short* gB = Bt + (size_t)(bn + srow) * 2048 + skg * 8;

  // ds_read fragment offsets (loop-invariant)
  int aoff[8], boff[4];
#pragma unroll
  for (int mi = 0; mi < 8; ++mi) aoff[mi] = lds_off(wr * 128 + mi * 16 + ln, qd);
#pragma unroll
  for (int ni = 0; ni < 4; ++ni) boff[ni] = lds_off(wc * 64 + ni * 16 + ln, qd);

  floatx4 acc[8][4];
#pragma unroll
  for (int i = 0; i < 8; ++i)
#pragma unroll
    for (int j = 0; j < 4; ++j) acc[i][j] = (floatx4){0.f, 0.f, 0.f, 0.f};

  // ---- prologue: stage tile0 -> buf0, tile1 -> buf1 (issue order = FIFO)
  {
    unsigned short* d = &Ls[0][0][wave * 512];
    gload_lds16(gA, d);                 gload_lds16(gA + 128 * 2048, d + 4096);
    d = &Ls[0][1][wave * 512];
    gload_lds16(gB, d);                 gload_lds16(gB + 128 * 2048, d + 4096);
    d = &Ls[1][0][wave * 512];
    gload_lds16(gA + 32, d);            gload_lds16(gA + 128 * 2048 + 32, d + 4096);
    d = &Ls[1][1][wave * 512];
    gload_lds16(gB + 32, d);            gload_lds16(gB + 128 * 2048 + 32, d + 4096);
  }
  asm volatile("s_waitcnt vmcnt(4)" ::: "memory");   // tile0 landed, tile1 in flight
  __builtin_amdgcn_s_barrier();

  int b = 0;
  for (int t = 0; t < NT; ++t) {
    const int b2 = (b >= 1) ? b - 1 : b + 2;         // (t+2)%3
    const unsigned short* la = &Ls[b][0][0];
    const unsigned short* lb = &Ls[b][1][0];
    const bool pf = (t + 2) < NT;
    const int k2 = (t + 2) << 5;
    // ---- phase 0: m-frags 0..3 x all n; stage t+2's A
    bf16x8 bfr[4], af[4];
#pragma unroll
    for (int ni = 0; ni < 4; ++ni) bfr[ni] = *(const bf16x8*)(lb + boff[ni]);
#pragma unroll
    for (int mi = 0; mi < 4; ++mi) af[mi] = *(const bf16x8*)(la + aoff[mi]);
    if (pf) {
      unsigned short* d = &Ls[b2][0][wave * 512];
      gload_lds16(gA + k2, d);
      gload_lds16(gA + 128 * 2048 + k2, d + 4096);
    }
    __builtin_amdgcn_s_barrier();
    __builtin_amdgcn_s_setprio(1);
#pragma unroll
    for (int mi = 0; mi < 4; ++mi)
#pragma unroll
      for (int ni = 0; ni < 4; ++ni)
        acc[mi][ni] = __builtin_amdgcn_mfma_f32_16x16x32_bf16(af[mi], bfr[ni], acc[mi][ni], 0, 0, 0);
    __builtin_amdgcn_s_setprio(0);
    __builtin_amdgcn_s_barrier();
    // ---- phase 1: m-frags 4..7 x all n; stage t+2's B
#pragma unroll
    for (int mi = 0; mi < 4; ++mi) af[mi] = *(const bf16x8*)(la + aoff[4 + mi]);
    if (pf) {
      unsigned short* d = &Ls[b2][1][wave * 512];
      gload_lds16(gB + k2, d);
      gload_lds16(gB + 128 * 2048 + k2, d + 4096);
    }
    __builtin_amdgcn_s_barrier();
    __builtin_amdgcn_s_setprio(1);
#pragma unroll
    for (int mi = 0; mi < 4; ++mi)
#pragma unroll
      for (int ni = 0; ni < 4; ++ni)
        acc[4 + mi][ni] = __builtin_amdgcn_mfma_f32_16x16x32_bf16(af[mi], bfr[ni], acc[4 + mi][ni], 0, 0, 0);
    __builtin_amdgcn_s_setprio(0);
    if (t + 1 < NT) {
      if (pf) asm volatile("s_waitcnt vmcnt(4)" ::: "memory");
      else    asm volatile("s_waitcnt vmcnt(0)" ::: "memory");
      __builtin_amdgcn_s_barrier();
    }
    b = (b == 2) ? 0 : b + 1;
  }
  // ---- epilogue
#pragma unroll
  for (int mi = 0; mi < 8; ++mi)
#pragma unroll
    for (int r = 0; r < 4; ++r) {
      size_t row = (size_t)(bm + wr * 128 + mi * 16 + qd * 4 + r);
#pragma unroll
      for (int ni = 0; ni < 4; ++ni) {
        int col = bn + wc * 64 + ni * 16 + ln;
        C[row * 4608 + col] = f2bf(acc[mi][ni][r]);
      }
    }
}

// ---------------- 6. out GEMM: 64x128 tiles, BK=32, triple-buffer, 4/CU -----
// A = ATT [4096][1536] bf16; Bt = WTO [2048][1536] bf16; C = d_out f32 [4096][2048].
// 1024 blocks (4 resident/CU), 256 thr = 4 waves (1M x 4N), per-wave 64x32.
// Keff by out-col tier: <256 -> 288 (padded; masked weights are zero),
// <1024 -> 768, else 1536. NT = Keff/32 in {9,24,48}, all divisible by 3.
// LDS: As[3][2048] + Bs[3][4096] shorts = 36 KiB. Counted vmcnt(3) boundary.
#define G2_VM3 asm volatile("s_waitcnt vmcnt(3)" ::: "memory")
#define G2_VM0 asm volatile("s_waitcnt vmcnt(0)" ::: "memory")

#define G2_STEP(AP, BP, AQ, BQ, STG, K2, FINQ)                                  \
  do {                                                                          \
    bf16x8 af[4], bfr[2];                                                       \
    _Pragma("unroll")                                                           \
    for (int mi = 0; mi < 4; ++mi) af[mi] = *(const bf16x8*)((AP) + aoff[mi]);  \
    _Pragma("unroll")                                                           \
    for (int ni = 0; ni < 2; ++ni) bfr[ni] = *(const bf16x8*)((BP) + boff[ni]); \
    if (STG) {                                                                  \
      gload_lds16(gAs + (K2), (AQ) + wave * 512);                               \
      gload_lds16(gBs + (K2), (BQ) + wave * 512);                               \
      gload_lds16(gBs + 64 * 1536 + (K2), (BQ) + 2048 + wave * 512);            \
    }                                                                           \
    __builtin_amdgcn_s_barrier();                                               \
    __builtin_amdgcn_s_setprio(1);                                              \
    _Pragma("unroll")                                                           \
    for (int mi = 0; mi < 4; ++mi)                                              \
      _Pragma("unroll")                                                         \
      for (int ni = 0; ni < 2; ++ni)                                            \
        acc[mi][ni] = __builtin_amdgcn_mfma_f32_16x16x32_bf16(af[mi], bfr[ni], acc[mi][ni], 0, 0, 0); \
    __builtin_amdgcn_s_setprio(0);                                              \
    if (FINQ) {                                                                 \
      if (STG) { G2_VM3; } else { G2_VM0; }                                     \
      __builtin_amdgcn_s_barrier();                                             \
    }                                                                           \
  } while (0)

__global__ __launch_bounds__(256) void k_gemm2(const unsigned short* __restrict__ A,
                                               const unsigned short* __restrict__ Bt,
                                               float* __restrict__ C) {
  __shared__ unsigned short As0[2048], As1[2048], As2[2048];
  __shared__ unsigned short Bs0[4096], Bs1[4096], Bs2[4096];
  const int tid = threadIdx.x;
  const int wave = tid >> 6, lane = tid & 63;
  const int qd = lane >> 4, ln = lane & 15;
  // LPT: 512 tier2 (NT=48), 384 tier1 (NT=24), 128 tier0 (NT=9).
  // Col-major within tier: 64 consecutive blocks share one B panel.
  const int idx = blockIdx.x;
  int bx, by, NT;
  if (idx < 512)      { bx = 8 + (idx >> 6); by = idx & 63; NT = 48; }
  else if (idx < 896) { int t = idx - 512; bx = 2 + (t >> 6); by = t & 63; NT = 24; }
  else                { int t = idx - 896; bx = t >> 6; by = t & 63; NT = 9; }
  const int bm = by * 64, bn = bx * 128;

  // staging source map (inverse of LDS swizzle)
  const int Lr = tid >> 3, sl = tid & 7;
  const int gg = sl ^ (Lr & 7);
  const int srow = 2 * Lr + (gg >> 2);        // 0..63
  const int skg = gg & 3;
  const unsigned short* gAs = A + (size_t)(bm + srow) * 1536 + skg * 8;
  const unsigned short* gBs = Bt + (size_t)(bn + srow) * 1536 + skg * 8;

  int aoff[4], boff[2];
#pragma unroll
  for (int mi = 0; mi < 4; ++mi) aoff[mi] = lds_off(mi * 16 + ln, qd);
#pragma unroll
  for (int ni = 0; ni < 2; ++ni) boff[ni] = lds_off(wave * 32 + ni * 16 + ln, qd);

  floatx4 acc[4][2];
#pragma unroll
  for (int i = 0; i < 4; ++i)
#pragma unroll
    for (int j = 0; j < 2; ++j) acc[i][j] = (floatx4){0.f, 0.f, 0.f, 0.f};

  // ---- prologue: tile0 -> buf0, tile1 -> buf1 (FIFO)
  gload_lds16(gAs, As0 + wave * 512);
  gload_lds16(gBs, Bs0 + wave * 512);
  gload_lds16(gBs + 64 * 1536, Bs0 + 2048 + wave * 512);
  gload_lds16(gAs + 32, As1 + wave * 512);
  gload_lds16(gBs + 32, Bs1 + wave * 512);
  gload_lds16(gBs + 64 * 1536 + 32, Bs1 + 2048 + wave * 512);
  G2_VM3;                                     // tile0 landed; tile1 in flight
  __builtin_amdgcn_s_barrier();

  const int NT3 = NT / 3;
  for (int i = 0; i < NT3; ++i) {
    const int t0 = 3 * i;
    G2_STEP(As0, Bs0, As2, Bs2, (t0 + 2) < NT, (t0 + 2) * 32, (t0 + 1) < NT);
    G2_STEP(As1, Bs1, As0, Bs0, (t0 + 3) < NT, (t0 + 3) * 32, (t0 + 2) < NT);
    G2_STEP(As2, Bs2, As1, Bs1, (t0 + 4) < NT, (t0 + 4) * 32, (t0 + 3) < NT);
  }

  // ---- epilogue: f32 C
#pragma unroll
  for (int mi = 0; mi < 4; ++mi)
#pragma unroll
    for (int r = 0; r < 4; ++r) {
      size_t row = (size_t)(bm + mi * 16 + qd * 4 + r);
#pragma unroll
      for (int ni = 0; ni < 2; ++ni) {
        int col = bn + wave * 32 + ni * 16 + ln;
        C[row * 2048 + col] = acc[mi][ni][r];
      }
    }
}

// ---------------- 4b. V transpose: VT[b][d(1536)][T] from QKV cols 3072+ ----
__global__ void k_transpose_v(const unsigned short* __restrict__ QKV,
                              unsigned short* __restrict__ VT) {
  __shared__ unsigned short t[64 * 65];
  const int tt = blockIdx.x * 64, dt = blockIdx.y * 64, b = blockIdx.z;
  const int tid = threadIdx.x;
  const int r = tid >> 3, c0 = (tid & 7) * 8;
#pragma unroll
  for (int i = 0; i < 2; ++i) {
    int tok = r + i * 32;
    union { uint4 v; unsigned short u[8]; } vv;
    vv.v = *(const uint4*)(QKV + (size_t)(b * 1024 + tt + tok) * 4608 + 3072 + dt + c0);
#pragma unroll
    for (int j = 0; j < 8; ++j) t[tok * 65 + c0 + j] = vv.u[j];
  }
  __syncthreads();
#pragma unroll
  for (int i = 0; i < 2; ++i) {
    int d = r + i * 32;
    union { uint4 v; unsigned short u[8]; } vv;
#pragma unroll
    for (int j = 0; j < 8; ++j) vv.u[j] = t[(c0 + j) * 65 + d];
    *(uint4*)(VT + ((size_t)b * 1536 + dt + d) * 1024 + tt + c0) = vv.v;
  }
}

// ---------------- 5. causal flash attention, 128q x 128k tiles --------------
// grid (8 qtiles [reversed], 24 heads, 4 batch), block 256 = 4 waves.
#define LDP 136
__global__ __launch_bounds__(256) void k_attn(const unsigned short* __restrict__ QKV,
                                              const unsigned short* __restrict__ VT,
                                              unsigned short* __restrict__ Oout) {
  __shared__ unsigned short Ks[128 * 64];     // [key][d], 8-grp XOR swizzle
  __shared__ unsigned short VTs[64 * 128];    // [d][key], 16-grp XOR swizzle
  __shared__ unsigned short Pl[4][16 * LDP];  // wave-private P staging
  const int tid = threadIdx.x;
  const int wave = tid >> 6, lane = tid & 63;
  const int qd = lane >> 4, ln = lane & 15;
  const int qb = (int)gridDim.x - 1 - (int)blockIdx.x;   // big blocks first
  const int gh = blockIdx.y, b = blockIdx.z;
  const int T = 1024, LD = 4608;
  const size_t rowbase = (size_t)b * T * LD;
  const int qcol = 64 * gh, kcol = 1536 + 64 * gh;
  const unsigned short* VTg = VT + ((size_t)b * 1536 + 64 * gh) * 1024;
  const float SCALE = 0.18033688f;  // 1/sqrt(64) * log2(e)
  const int q0 = qb * 128 + wave * 16;       // frag j adds j*64

  bf16x8 aq[2][2];
#pragma unroll
  for (int j = 0; j < 2; ++j) {
    const unsigned short* qp = QKV + rowbase + (size_t)(q0 + j * 64 + ln) * LD + qcol;
    aq[j][0] = *(const bf16x8*)(qp + qd * 8);
    aq[j][1] = *(const bf16x8*)(qp + 32 + qd * 8);
  }
  floatx4 Oacc[2][4];
#pragma unroll
  for (int j = 0; j < 2; ++j)
#pragma unroll
    for (int i = 0; i < 4; ++i) Oacc[j][i] = (floatx4){0.f, 0.f, 0.f, 0.f};
  float l_lane[2] = {0.f, 0.f};

  // K staging: wave stages rows [wave*32, +32) (4 gloads x 8 rows)
  const int rk = lane >> 3;                   // 0..7
  const int gk = ((lane & 7) ^ rk) * 8;       // swizzled source group (8-grp)
  const unsigned short* gK = QKV + rowbase + (size_t)(wave * 32 + rk) * LD + kcol + gk;
  unsigned short* lK = Ks + wave * 32 * 64;
  // VT staging: wave stages d-rows [wave*16, +16) (4 gloads x 4 rows x 128 c)
  const int rv = lane >> 4;                   // 0..3
  const int cv = lane & 15;
  unsigned short* lV = VTs + wave * 16 * 128;
  const unsigned short* gVrow[4];
  int gvcol[4];
#pragma unroll
  for (int i = 0; i < 4; ++i) {
    int d = wave * 16 + 4 * i + rv;
    gVrow[i] = VTg + (size_t)d * 1024;
    gvcol[i] = (cv ^ (4 * i + rv)) * 8;       // 16-grp swizzle by d&15
  }
  const int l7 = ln & 7;

  for (int jt = 0; jt <= qb; ++jt) {
    const int jk = jt * 128;
    const bool diag = (jt == qb);
    __syncthreads();
#pragma unroll
    for (int i = 0; i < 4; ++i) {
      gload_lds16(gK + (size_t)(jk + 8 * i) * LD, lK + i * 512);
      gload_lds16(gVrow[i] + jk + gvcol[i], lV + i * 512);
    }
    __syncthreads();

#pragma unroll
    for (int j = 0; j < 2; ++j) {
      const bool dj0 = diag && (j == 0);
      const int hmax = dj0 ? 4 : 8;
      // S^T = K Q^T : A = K[key][d] (frag h = keys h*16..+16), B = Q
      floatx4 Sc[8];
#pragma unroll
      for (int h = 0; h < 8; ++h) {
        if (h >= hmax) continue;
        Sc[h] = (floatx4){0.f, 0.f, 0.f, 0.f};
        bf16x8 a0 = *(const bf16x8*)(Ks + (h * 16 + ln) * 64 + (qd ^ l7) * 8);
        bf16x8 a1 = *(const bf16x8*)(Ks + (h * 16 + ln) * 64 + ((4 + qd) ^ l7) * 8);
        Sc[h] = __builtin_amdgcn_mfma_f32_16x16x32_bf16(a0, aq[j][0], Sc[h], 0, 0, 0);
        Sc[h] = __builtin_amdgcn_mfma_f32_16x16x32_bf16(a1, aq[j][1], Sc[h], 0, 0, 0);
      }
      const int qrow = q0 + j * 64 + ln;
      unsigned short* pw = Pl[wave];
#pragma unroll
      for (int h = 0; h < 8; ++h) {
        if (h >= hmax) continue;
        union { unsigned short u[4]; uint2 v; } pk;
#pragma unroll
        for (int r = 0; r < 4; ++r) {
          float v = fminf(Sc[h][r] * SCALE, 80.f);
          float p = __builtin_amdgcn_exp2f(v);
          if (diag && (j == 0 || h >= 4)) {
            int key = jk + h * 16 + qd * 4 + r;
            if (key > qrow) p = 0.f;
          }
          l_lane[j] += p;
          pk.u[r] = f2bf(p);
        }
        *(uint2*)(pw + ln * LDP + h * 16 + qd * 4) = pk.v;
      }
      __asm__ volatile("s_waitcnt lgkmcnt(0)" ::: "memory");
      const int smax = dj0 ? 2 : 4;
      bf16x8 pa[4];
#pragma unroll
      for (int s = 0; s < 4; ++s) {
        if (s >= smax) continue;
        pa[s] = *(const bf16x8*)(pw + ln * LDP + s * 32 + qd * 8);
      }
#pragma unroll
      for (int nc = 0; nc < 4; ++nc) {
        const int d = nc * 16 + ln;
#pragma unroll
        for (int s = 0; s < 4; ++s) {
          if (s >= smax) continue;
          bf16x8 bv = *(const bf16x8*)(VTs + d * 128 + (((s * 4 + qd) ^ ln) & 15) * 8);
          Oacc[j][nc] = __builtin_amdgcn_mfma_f32_16x16x32_bf16(pa[s], bv, Oacc[j][nc], 0, 0, 0);
        }
      }
    }
  }
  // l: sum the 4 qd-groups per ln, then normalize + store
#pragma unroll
  for (int j = 0; j < 2; ++j) {
    float l = l_lane[j];
    l += __shfl_xor(l, 16, 64);
    l += __shfl_xor(l, 32, 64);
#pragma unroll
    for (int r = 0; r < 4; ++r) {
      float inv = 1.0f / __shfl(l, qd * 4 + r, 64);
      size_t row = (size_t)b * T + q0 + j * 64 + qd * 4 + r;
#pragma unroll
      for (int nc = 0; nc < 4; ++nc)
        Oout[row * 1536 + 64 * gh + nc * 16 + ln] = f2bf(Oacc[j][nc][r] * inv);
    }
  }
}

// ---------------------------------------------------------------------------
extern "C" void kernel_launch(void* const* d_in, const int* in_sizes, int n_in,
                              void* d_out, int out_size, void* d_ws, size_t ws_size,
                              hipStream_t stream) {
  (void)in_sizes; (void)n_in; (void)out_size; (void)ws_size;
  const float* x   = (const float*)d_in[0];
  const float* WQ  = (const float*)d_in[1];
  const float* WK  = (const float*)d_in[2];
  const float* WV  = (const float*)d_in[3];
  const float* WO  = (const float*)d_in[4];
  const float* FK0 = (const float*)d_in[5];
  const float* PK0 = (const float*)d_in[6];
  const float* FV0 = (const float*)d_in[7];
  const float* PV0 = (const float*)d_in[8];
  const float* FK1 = (const float*)d_in[9];
  const float* PK1 = (const float*)d_in[10];
  const float* FV1 = (const float*)d_in[11];
  const float* PV1 = (const float*)d_in[12];

  char* ws = (char*)d_ws;
  unsigned short* X16   = (unsigned short*)(ws + 0);          // 16 MB (dead after GEMM1)
  unsigned short* VTb   = X16;                                 // VT aliases X16
  unsigned short* WTQKV = (unsigned short*)(ws + 16777216);   // 18 MB
  unsigned short* QKV   = (unsigned short*)(ws + 35651584);   // 36 MB
  unsigned short* ATT   = (unsigned short*)(ws + 73400320);   // 12 MB
  unsigned short* WTO   = (unsigned short*)(ws + 85983232);   //  6 MB

  k_prep<<<20480, 256, 0, stream>>>(x, X16, WQ, WK, WV,
                                    FK0, PK0, FV0, PV0, FK1, PK1, FV1, PV1,
                                    WTQKV, WO, WTO);
  k_gemm1<<<288, 512, 0, stream>>>(X16, WTQKV, QKV);
  k_transpose_v<<<dim3(16, 24, 4), 256, 0, stream>>>(QKV, VTb);
  k_attn<<<dim3(8, 24, 4), 256, 0, stream>>>(QKV, VTb, ATT);
  k_gemm2<<<1024, 256, 0, stream>>>(ATT, WTO, (float*)d_out);
}

// Round 6
// 318.961 us; speedup vs baseline: 1.0950x; 1.0509x over previous
//
#include <hip/hip_runtime.h>

// ---------------------------------------------------------------------------
// MatryoshkaAttention on MI355X (gfx950), bf16 MFMA pipeline. Round 12.
//
// R12 = R0/R6 configuration REVERTED (totals proved the 256-tile gemm1 and the
// counted-vmcnt gemm2 were net-negative: 323.0 -> 333.3 -> 335.2), plus ONE
// change: XCD-chunked 2D-blocked dispatch for both GEMMs (guide T1).
//   block b -> XCD b&7 (HW round-robin); each XCD gets a contiguous 2D
//   sub-rectangle of each Keff tier (long tiers first per XCD = LPT kept).
//   Concurrent per-XCD working set drops ~31 MB -> ~6 MB => panel re-reads
//   become L2 hits. Bijective remap only; kernel bodies are R0 exact.
// ---------------------------------------------------------------------------

typedef short bf16x8 __attribute__((ext_vector_type(8)));
typedef float floatx4 __attribute__((ext_vector_type(4)));

__device__ __forceinline__ unsigned short f2bf(float f) {
  unsigned u = __builtin_bit_cast(unsigned, f);
  u += 0x7fffu + ((u >> 16) & 1u);           // RNE
  return (unsigned short)(u >> 16);
}

__device__ __forceinline__ void gload_lds16(const unsigned short* g, unsigned short* l) {
  __builtin_amdgcn_global_load_lds((const __attribute__((address_space(1))) unsigned int*)g,
                                   (__attribute__((address_space(3))) unsigned int*)l, 16, 0, 0);
}

// ---------------- 1. fused prep: cvt_x | pack_qkv(+corr) | pack_o ----------
// blocks [0,8192): x->bf16 ; [8192,17408): W_QKV pack ; [17408,20480): W_O.
__global__ __launch_bounds__(256) void k_prep(
    const float* __restrict__ x, unsigned short* __restrict__ X16,
    const float* __restrict__ WQ, const float* __restrict__ WK, const float* __restrict__ WV,
    const float* __restrict__ FK0, const float* __restrict__ PK0,
    const float* __restrict__ FV0, const float* __restrict__ PV0,
    const float* __restrict__ FK1, const float* __restrict__ PK1,
    const float* __restrict__ FV1, const float* __restrict__ PV1,
    unsigned short* __restrict__ WTQKV,
    const float* __restrict__ WO, unsigned short* __restrict__ WTO) {
  __shared__ float tile[32][33];
  __shared__ float Fs[32][9];
  __shared__ float Ps[8][32];
  const int bid = blockIdx.x;
  const int tid = threadIdx.x;
  if (bid < 8192) {                       // ---- x -> bf16 (float4 per thread)
    int i = bid * 256 + tid;
    float4 v = ((const float4*)x)[i];
    union { unsigned short u[4]; uint2 v2; } o;
    o.u[0] = f2bf(v.x); o.u[1] = f2bf(v.y); o.u[2] = f2bf(v.z); o.u[3] = f2bf(v.w);
    ((uint2*)X16)[i] = o.v2;
    return;
  }
  const int tx = tid & 31, ty = tid >> 5;
  if (bid < 17408) {                      // ---- W_QKV transpose + corrections
    int t = bid - 8192;
    int k0 = (t & 63) * 32, n0 = (t >> 6) * 32;
    const float* src; int nboff;
    if (n0 < 1536)      { src = WQ; nboff = n0; }
    else if (n0 < 3072) { src = WK; nboff = n0 - 1536; }
    else                { src = WV; nboff = n0 - 3072; }
#pragma unroll
    for (int j = 0; j < 4; ++j) {
      int kk = ty + j * 8;
      tile[kk][tx] = src[(size_t)(k0 + kk) * 1536 + nboff + tx];
    }
    int corrsel = 0; const float* Fsrc = nullptr; const float* Psrc = nullptr;
    int h = 0, d0 = 0, fs = 0, koff = 0;
    if (n0 >= 1536) {
      bool isK = (n0 < 3072);
      int np0 = isK ? (n0 - 1536) : (n0 - 3072);
      if (np0 < 256) {
        if (k0 >= 256) { corrsel = 1; Fsrc = isK ? FK0 : FV0; Psrc = isK ? PK0 : PV0;
                         h = np0 >> 6; d0 = np0 & 63; fs = 32; koff = k0 - 256; }
      } else if (np0 < 768) {
        if (k0 >= 1024) { corrsel = 1; Fsrc = isK ? FK1 : FV1; Psrc = isK ? PK1 : PV1;
                          h = (np0 - 256) >> 6; d0 = (np0 - 256) & 63; fs = 64; koff = k0 - 1024; }
      }
    }
    if (corrsel) {
      Fs[tid >> 3][tid & 7] = Fsrc[(size_t)(koff + (tid >> 3)) * fs + h * 8 + (tid & 7)];
      Ps[tid >> 5][tid & 31] = Psrc[h * 512 + (tid >> 5) * 64 + d0 + (tid & 31)];
    }
    __syncthreads();
#pragma unroll
    for (int j = 0; j < 4; ++j) {
      int nn = ty + j * 8;
      float v = tile[tx][nn];
      if (corrsel) {
        float c = 0.f;
#pragma unroll
        for (int r = 0; r < 8; ++r) c += Fs[tx][r] * Ps[r][nn];
        v += c;
      }
      WTQKV[(size_t)(n0 + nn) * 2048 + k0 + tx] = f2bf(v);
    }
  } else {                                // ---- W_O transpose
    int t = bid - 17408;
    int k0 = (t % 48) * 32, n0 = (t / 48) * 32;
#pragma unroll
    for (int j = 0; j < 4; ++j)
      tile[ty + j * 8][tx] = WO[(size_t)(k0 + ty + j * 8) * 2048 + n0 + tx];
    __syncthreads();
#pragma unroll
    for (int j = 0; j < 4; ++j)
      WTO[(size_t)(n0 + ty + j * 8) * 1536 + k0 + tx] = f2bf(tile[tx][ty + j * 8]);
  }
}

// ---------------- 4/6. GEMM BK=64, Keff per column block -------------------
// XCD-chunked 2D dispatch: xcd = idx&7 (HW round-robin), r = idx>>3 ranks
// within the XCD, long tiers first (LPT per XCD). Each XCD's long chunk is a
// 2D sub-rectangle (6-wide / 4-wide column groups) so its ~32 concurrent
// blocks share ~6 A-panels + ~6 B-panels (~6 MB) in its private L2.
// MODE 0: QKV (N=4608, 36 cols; 1152 blocks = 8 x 144)
// MODE 1: out (N=2048, 16 cols;  512 blocks = 8 x 64)
template <bool OUT_BF16, int MODE>
__global__ __launch_bounds__(256) void k_gemm_bt(const unsigned short* __restrict__ A,
                                                 const unsigned short* __restrict__ Bt,
                                                 void* __restrict__ C, int M, int N, int K) {
  __shared__ unsigned short As[128 * 64];
  __shared__ unsigned short Bs[128 * 64];
  const int tid = threadIdx.x;
  const int wave = tid >> 6, lane = tid & 63;
  const int qd = lane >> 4, ln = lane & 15;
  const int idx = blockIdx.x;
  const int xcd = idx & 7, r = idx >> 3;
  int bx, by;
  if (MODE == 0) {
    if (r < 120) {                 // long: Keff=2048, 960 blocks = 5 scol x (6bx x 32by)
      int L = xcd * 120 + r;
      int scol = L / 192, q = L % 192;
      by = q / 6; bx = 6 + scol * 6 + q % 6;
    } else {
      int ms = xcd * 24 + (r - 120);          // 0..191
      if (ms < 128) { bx = 2 + (ms & 3); by = ms >> 2; }   // mid: Keff=1024
      else          { int sh = ms - 128; bx = sh & 1; by = sh >> 1; } // short
    }
  } else {
    if (r < 32) {                  // long: Keff=1536, 256 blocks = 2 scol x (4bx x 32by)
      int L = xcd * 32 + r;
      int scol = L >> 7, q = L & 127;
      by = q >> 2; bx = 8 + scol * 4 + (q & 3);
    } else if (r < 56) {
      int m = xcd * 24 + (r - 32);            // 0..191, mid: Keff=768
      bx = 2 + m % 6; by = m / 6;
    } else {
      int sh = xcd * 8 + (r - 56);            // 0..63, short: Keff=256
      bx = sh & 1; by = sh >> 1;
    }
  }
  const int bm = by * 128, bn = bx * 128;
  const int wr = wave >> 1, wc = wave & 1;
  int Keff;
  if (MODE == 0) Keff = (bn < 256) ? 256 : (bn < 768 ? 1024 : 2048);
  else           Keff = (bn < 256) ? 256 : (bn < 1024 ? 768 : 1536);
  floatx4 acc[4][4];
#pragma unroll
  for (int i = 0; i < 4; ++i)
#pragma unroll
    for (int j = 0; j < 4; ++j) acc[i][j] = (floatx4){0.f, 0.f, 0.f, 0.f};
  const int rl = lane >> 3;                        // row mod 8
  const int sg = (lane & 7) ^ rl;                  // swizzled source group
  const unsigned short* gA = A + (size_t)(bm + wave * 32 + rl) * K + sg * 8;
  const unsigned short* gB = Bt + (size_t)(bn + wave * 32 + rl) * K + sg * 8;
  unsigned short* lA = As + wave * 2048;
  unsigned short* lB = Bs + wave * 2048;
  const int l7 = ln & 7;
  for (int k0 = 0; k0 < Keff; k0 += 64) {
    __syncthreads();
#pragma unroll
    for (int i = 0; i < 4; ++i) {
      gload_lds16(gA + (size_t)8 * i * K + k0, lA + i * 512);
      gload_lds16(gB + (size_t)8 * i * K + k0, lB + i * 512);
    }
    __syncthreads();
#pragma unroll
    for (int h = 0; h < 2; ++h) {
      bf16x8 af[4], bfr[4];
#pragma unroll
      for (int mi = 0; mi < 4; ++mi)
        af[mi] = *(const bf16x8*)(As + (wr * 64 + mi * 16 + ln) * 64 + ((h * 4 + qd) ^ l7) * 8);
#pragma unroll
      for (int ni = 0; ni < 4; ++ni)
        bfr[ni] = *(const bf16x8*)(Bs + (wc * 64 + ni * 16 + ln) * 64 + ((h * 4 + qd) ^ l7) * 8);
#pragma unroll
      for (int mi = 0; mi < 4; ++mi)
#pragma unroll
        for (int ni = 0; ni < 4; ++ni)
          acc[mi][ni] = __builtin_amdgcn_mfma_f32_16x16x32_bf16(af[mi], bfr[ni], acc[mi][ni], 0, 0, 0);
    }
  }
#pragma unroll
  for (int mi = 0; mi < 4; ++mi)
#pragma unroll
    for (int r2 = 0; r2 < 4; ++r2) {
      int row = bm + wr * 64 + mi * 16 + qd * 4 + r2;
#pragma unroll
      for (int ni = 0; ni < 4; ++ni) {
        int col = bn + wc * 64 + ni * 16 + ln;
        if (OUT_BF16)
          ((unsigned short*)C)[(size_t)row * N + col] = f2bf(acc[mi][ni][r2]);
        else
          ((float*)C)[(size_t)row * N + col] = acc[mi][ni][r2];
      }
    }
}

// ---------------- 4b. V transpose: VT[b][d(1536)][T] from QKV cols 3072+ ----
__global__ void k_transpose_v(const unsigned short* __restrict__ QKV,
                              unsigned short* __restrict__ VT) {
  __shared__ unsigned short t[64 * 65];
  const int tt = blockIdx.x * 64, dt = blockIdx.y * 64, b = blockIdx.z;
  const int tid = threadIdx.x;
  const int r = tid >> 3, c0 = (tid & 7) * 8;
#pragma unroll
  for (int i = 0; i < 2; ++i) {
    int tok = r + i * 32;
    union { uint4 v; unsigned short u[8]; } vv;
    vv.v = *(const uint4*)(QKV + (size_t)(b * 1024 + tt + tok) * 4608 + 3072 + dt + c0);
#pragma unroll
    for (int j = 0; j < 8; ++j) t[tok * 65 + c0 + j] = vv.u[j];
  }
  __syncthreads();
#pragma unroll
  for (int i = 0; i < 2; ++i) {
    int d = r + i * 32;
    union { uint4 v; unsigned short u[8]; } vv;
#pragma unroll
    for (int j = 0; j < 8; ++j) vv.u[j] = t[(c0 + j) * 65 + d];
    *(uint4*)(VT + ((size_t)b * 1536 + dt + d) * 1024 + tt + c0) = vv.v;
  }
}

// ---------------- 5. causal flash attention, 128q x 128k tiles --------------
// grid (8 qtiles [reversed], 24 heads, 4 batch), block 256 = 4 waves.
// Wave: 2 q-frags (16 rows, 64 apart). No-max exp2 softmax, deferred l.
// Diagonal tile: frag0 computes keys [0,64) only; frag1 masks keys >= 64.
#define LDP 136
__global__ __launch_bounds__(256) void k_attn(const unsigned short* __restrict__ QKV,
                                              const unsigned short* __restrict__ VT,
                                              unsigned short* __restrict__ Oout) {
  __shared__ unsigned short Ks[128 * 64];     // [key][d], 8-grp XOR swizzle
  __shared__ unsigned short VTs[64 * 128];    // [d][key], 16-grp XOR swizzle
  __shared__ unsigned short Pl[4][16 * LDP];  // wave-private P staging
  const int tid = threadIdx.x;
  const int wave = tid >> 6, lane = tid & 63;
  const int qd = lane >> 4, ln = lane & 15;
  const int qb = (int)gridDim.x - 1 - (int)blockIdx.x;   // big blocks first
  const int gh = blockIdx.y, b = blockIdx.z;
  const int T = 1024, LD = 4608;
  const size_t rowbase = (size_t)b * T * LD;
  const int qcol = 64 * gh, kcol = 1536 + 64 * gh;
  const unsigned short* VTg = VT + ((size_t)b * 1536 + 64 * gh) * 1024;
  const float SCALE = 0.18033688f;  // 1/sqrt(64) * log2(e)
  const int q0 = qb * 128 + wave * 16;       // frag j adds j*64

  bf16x8 aq[2][2];
#pragma unroll
  for (int j = 0; j < 2; ++j) {
    const unsigned short* qp = QKV + rowbase + (size_t)(q0 + j * 64 + ln) * LD + qcol;
    aq[j][0] = *(const bf16x8*)(qp + qd * 8);
    aq[j][1] = *(const bf16x8*)(qp + 32 + qd * 8);
  }
  floatx4 Oacc[2][4];
#pragma unroll
  for (int j = 0; j < 2; ++j)
#pragma unroll
    for (int i = 0; i < 4; ++i) Oacc[j][i] = (floatx4){0.f, 0.f, 0.f, 0.f};
  float l_lane[2] = {0.f, 0.f};

  // K staging: wave stages rows [wave*32, +32) (4 gloads x 8 rows)
  const int rk = lane >> 3;                   // 0..7
  const int gk = ((lane & 7) ^ rk) * 8;       // swizzled source group (8-grp)
  const unsigned short* gK = QKV + rowbase + (size_t)(wave * 32 + rk) * LD + kcol + gk;
  unsigned short* lK = Ks + wave * 32 * 64;
  // VT staging: wave stages d-rows [wave*16, +16) (4 gloads x 4 rows x 128 c)
  const int rv = lane >> 4;                   // 0..3
  const int cv = lane & 15;
  unsigned short* lV = VTs + wave * 16 * 128;
  const unsigned short* gVrow[4];
  int gvcol[4];
#pragma unroll
  for (int i = 0; i < 4; ++i) {
    int d = wave * 16 + 4 * i + rv;
    gVrow[i] = VTg + (size_t)d * 1024;
    gvcol[i] = (cv ^ (4 * i + rv)) * 8;       // 16-grp swizzle by d&15
  }
  const int l7 = ln & 7;

  for (int jt = 0; jt <= qb; ++jt) {
    const int jk = jt * 128;
    const bool diag = (jt == qb);
    __syncthreads();
#pragma unroll
    for (int i = 0; i < 4; ++i) {
      gload_lds16(gK + (size_t)(jk + 8 * i) * LD, lK + i * 512);
      gload_lds16(gVrow[i] + jk + gvcol[i], lV + i * 512);
    }
    __syncthreads();

#pragma unroll
    for (int j = 0; j < 2; ++j) {
      const bool dj0 = diag && (j == 0);
      const int hmax = dj0 ? 4 : 8;
      // S^T = K Q^T : A = K[key][d] (frag h = keys h*16..+16), B = Q
      floatx4 Sc[8];
#pragma unroll
      for (int h = 0; h < 8; ++h) {
        if (h >= hmax) continue;
        Sc[h] = (floatx4){0.f, 0.f, 0.f, 0.f};
        bf16x8 a0 = *(const bf16x8*)(Ks + (h * 16 + ln) * 64 + (qd ^ l7) * 8);
        bf16x8 a1 = *(const bf16x8*)(Ks + (h * 16 + ln) * 64 + ((4 + qd) ^ l7) * 8);
        Sc[h] = __builtin_amdgcn_mfma_f32_16x16x32_bf16(a0, aq[j][0], Sc[h], 0, 0, 0);
        Sc[h] = __builtin_amdgcn_mfma_f32_16x16x32_bf16(a1, aq[j][1], Sc[h], 0, 0, 0);
      }
      const int qrow = q0 + j * 64 + ln;
      unsigned short* pw = Pl[wave];
#pragma unroll
      for (int h = 0; h < 8; ++h) {
        if (h >= hmax) continue;
        union { unsigned short u[4]; uint2 v; } pk;
#pragma unroll
        for (int r = 0; r < 4; ++r) {
          float v = fminf(Sc[h][r] * SCALE, 80.f);
          float p = __builtin_amdgcn_exp2f(v);
          if (diag && (j == 0 || h >= 4)) {
            int key = jk + h * 16 + qd * 4 + r;
            if (key > qrow) p = 0.f;
          }
          l_lane[j] += p;
          pk.u[r] = f2bf(p);
        }
        *(uint2*)(pw + ln * LDP + h * 16 + qd * 4) = pk.v;
      }
      __asm__ volatile("s_waitcnt lgkmcnt(0)" ::: "memory");
      const int smax = dj0 ? 2 : 4;
      bf16x8 pa[4];
#pragma unroll
      for (int s = 0; s < 4; ++s) {
        if (s >= smax) continue;
        pa[s] = *(const bf16x8*)(pw + ln * LDP + s * 32 + qd * 8);
      }
#pragma unroll
      for (int nc = 0; nc < 4; ++nc) {
        const int d = nc * 16 + ln;
#pragma unroll
        for (int s = 0; s < 4; ++s) {
          if (s >= smax) continue;
          bf16x8 bv = *(const bf16x8*)(VTs + d * 128 + (((s * 4 + qd) ^ ln) & 15) * 8);
          Oacc[j][nc] = __builtin_amdgcn_mfma_f32_16x16x32_bf16(pa[s], bv, Oacc[j][nc], 0, 0, 0);
        }
      }
    }
  }
  // l: sum the 4 qd-groups per ln, then normalize + store
#pragma unroll
  for (int j = 0; j < 2; ++j) {
    float l = l_lane[j];
    l += __shfl_xor(l, 16, 64);
    l += __shfl_xor(l, 32, 64);
#pragma unroll
    for (int r = 0; r < 4; ++r) {
      float inv = 1.0f / __shfl(l, qd * 4 + r, 64);
      size_t row = (size_t)b * T + q0 + j * 64 + qd * 4 + r;
#pragma unroll
      for (int nc = 0; nc < 4; ++nc)
        Oout[row * 1536 + 64 * gh + nc * 16 + ln] = f2bf(Oacc[j][nc][r] * inv);
    }
  }
}

// ---------------------------------------------------------------------------
extern "C" void kernel_launch(void* const* d_in, const int* in_sizes, int n_in,
                              void* d_out, int out_size, void* d_ws, size_t ws_size,
                              hipStream_t stream) {
  (void)in_sizes; (void)n_in; (void)out_size; (void)ws_size;
  const float* x   = (const float*)d_in[0];
  const float* WQ  = (const float*)d_in[1];
  const float* WK  = (const float*)d_in[2];
  const float* WV  = (const float*)d_in[3];
  const float* WO  = (const float*)d_in[4];
  const float* FK0 = (const float*)d_in[5];
  const float* PK0 = (const float*)d_in[6];
  const float* FV0 = (const float*)d_in[7];
  const float* PV0 = (const float*)d_in[8];
  const float* FK1 = (const float*)d_in[9];
  const float* PK1 = (const float*)d_in[10];
  const float* FV1 = (const float*)d_in[11];
  const float* PV1 = (const float*)d_in[12];

  char* ws = (char*)d_ws;
  unsigned short* X16   = (unsigned short*)(ws + 0);          // 16 MB (dead after GEMM1)
  unsigned short* VTb   = X16;                                 // VT aliases X16
  unsigned short* WTQKV = (unsigned short*)(ws + 16777216);   // 18 MB
  unsigned short* QKV   = (unsigned short*)(ws + 35651584);   // 36 MB
  unsigned short* ATT   = (unsigned short*)(ws + 73400320);   // 12 MB
  unsigned short* WTO   = (unsigned short*)(ws + 85983232);   //  6 MB

  k_prep<<<20480, 256, 0, stream>>>(x, X16, WQ, WK, WV,
                                    FK0, PK0, FV0, PV0, FK1, PK1, FV1, PV1,
                                    WTQKV, WO, WTO);
  k_gemm_bt<true, 0><<<1152, 256, 0, stream>>>(X16, WTQKV, QKV, 4096, 4608, 2048);
  k_transpose_v<<<dim3(16, 24, 4), 256, 0, stream>>>(QKV, VTb);
  k_attn<<<dim3(8, 24, 4), 256, 0, stream>>>(QKV, VTb, ATT);
  k_gemm_bt<false, 1><<<512, 256, 0, stream>>>(ATT, WTO, d_out, 4096, 2048, 1536);
}

// Round 7
// 303.588 us; speedup vs baseline: 1.1504x; 1.0506x over previous
//
#include <hip/hip_runtime.h>

// ---------------------------------------------------------------------------
// MatryoshkaAttention on MI355X (gfx950), bf16 MFMA pipeline. Round 13.
//
// Changes vs R12 (kernel bodies of the GEMM inner loop untouched):
//  - k_transpose_v ELIMINATED: gemm M0's V-column blocks (bn>=3072) write VT
//    [b][d][t] directly via an in-LDS per-wave 64x64 transpose (As/Bs reused
//    as scratch after one barrier; XOR-swizzled 8-chunk layout -> 2-way max
//    bank aliasing; 16B-coalesced VT stores). QKV buffer shrinks to Q+K only
//    (LD 3072); VT gets its own region (X16 alias removed; ws total same).
//  - k_attn grid (8,24,4) -> (24,4,8): qtile is the slowest axis, so all 8
//    qtiles of a (head,batch) land on the SAME XCD (96 % 8 == 0) => that
//    XCD's 12 K/V pairs (~3 MB) stay L2-resident across rounds. qb = 7-z
//    keeps longest-first. (Same T1 fix that won R12 for the GEMMs.)
// ---------------------------------------------------------------------------

typedef short bf16x8 __attribute__((ext_vector_type(8)));
typedef float floatx4 __attribute__((ext_vector_type(4)));

__device__ __forceinline__ unsigned short f2bf(float f) {
  unsigned u = __builtin_bit_cast(unsigned, f);
  u += 0x7fffu + ((u >> 16) & 1u);           // RNE
  return (unsigned short)(u >> 16);
}

__device__ __forceinline__ void gload_lds16(const unsigned short* g, unsigned short* l) {
  __builtin_amdgcn_global_load_lds((const __attribute__((address_space(1))) unsigned int*)g,
                                   (__attribute__((address_space(3))) unsigned int*)l, 16, 0, 0);
}

// ---------------- 1. fused prep: cvt_x | pack_qkv(+corr) | pack_o ----------
// blocks [0,8192): x->bf16 ; [8192,17408): W_QKV pack ; [17408,20480): W_O.
__global__ __launch_bounds__(256) void k_prep(
    const float* __restrict__ x, unsigned short* __restrict__ X16,
    const float* __restrict__ WQ, const float* __restrict__ WK, const float* __restrict__ WV,
    const float* __restrict__ FK0, const float* __restrict__ PK0,
    const float* __restrict__ FV0, const float* __restrict__ PV0,
    const float* __restrict__ FK1, const float* __restrict__ PK1,
    const float* __restrict__ FV1, const float* __restrict__ PV1,
    unsigned short* __restrict__ WTQKV,
    const float* __restrict__ WO, unsigned short* __restrict__ WTO) {
  __shared__ float tile[32][33];
  __shared__ float Fs[32][9];
  __shared__ float Ps[8][32];
  const int bid = blockIdx.x;
  const int tid = threadIdx.x;
  if (bid < 8192) {                       // ---- x -> bf16 (float4 per thread)
    int i = bid * 256 + tid;
    float4 v = ((const float4*)x)[i];
    union { unsigned short u[4]; uint2 v2; } o;
    o.u[0] = f2bf(v.x); o.u[1] = f2bf(v.y); o.u[2] = f2bf(v.z); o.u[3] = f2bf(v.w);
    ((uint2*)X16)[i] = o.v2;
    return;
  }
  const int tx = tid & 31, ty = tid >> 5;
  if (bid < 17408) {                      // ---- W_QKV transpose + corrections
    int t = bid - 8192;
    int k0 = (t & 63) * 32, n0 = (t >> 6) * 32;
    const float* src; int nboff;
    if (n0 < 1536)      { src = WQ; nboff = n0; }
    else if (n0 < 3072) { src = WK; nboff = n0 - 1536; }
    else                { src = WV; nboff = n0 - 3072; }
#pragma unroll
    for (int j = 0; j < 4; ++j) {
      int kk = ty + j * 8;
      tile[kk][tx] = src[(size_t)(k0 + kk) * 1536 + nboff + tx];
    }
    int corrsel = 0; const float* Fsrc = nullptr; const float* Psrc = nullptr;
    int h = 0, d0 = 0, fs = 0, koff = 0;
    if (n0 >= 1536) {
      bool isK = (n0 < 3072);
      int np0 = isK ? (n0 - 1536) : (n0 - 3072);
      if (np0 < 256) {
        if (k0 >= 256) { corrsel = 1; Fsrc = isK ? FK0 : FV0; Psrc = isK ? PK0 : PV0;
                         h = np0 >> 6; d0 = np0 & 63; fs = 32; koff = k0 - 256; }
      } else if (np0 < 768) {
        if (k0 >= 1024) { corrsel = 1; Fsrc = isK ? FK1 : FV1; Psrc = isK ? PK1 : PV1;
                          h = (np0 - 256) >> 6; d0 = (np0 - 256) & 63; fs = 64; koff = k0 - 1024; }
      }
    }
    if (corrsel) {
      Fs[tid >> 3][tid & 7] = Fsrc[(size_t)(koff + (tid >> 3)) * fs + h * 8 + (tid & 7)];
      Ps[tid >> 5][tid & 31] = Psrc[h * 512 + (tid >> 5) * 64 + d0 + (tid & 31)];
    }
    __syncthreads();
#pragma unroll
    for (int j = 0; j < 4; ++j) {
      int nn = ty + j * 8;
      float v = tile[tx][nn];
      if (corrsel) {
        float c = 0.f;
#pragma unroll
        for (int r = 0; r < 8; ++r) c += Fs[tx][r] * Ps[r][nn];
        v += c;
      }
      WTQKV[(size_t)(n0 + nn) * 2048 + k0 + tx] = f2bf(v);
    }
  } else {                                // ---- W_O transpose
    int t = bid - 17408;
    int k0 = (t % 48) * 32, n0 = (t / 48) * 32;
#pragma unroll
    for (int j = 0; j < 4; ++j)
      tile[ty + j * 8][tx] = WO[(size_t)(k0 + ty + j * 8) * 2048 + n0 + tx];
    __syncthreads();
#pragma unroll
    for (int j = 0; j < 4; ++j)
      WTO[(size_t)(n0 + ty + j * 8) * 1536 + k0 + tx] = f2bf(tile[tx][ty + j * 8]);
  }
}

// ---------------- 4/6. GEMM BK=64, Keff per column block, XCD-chunked -------
// MODE 0: QKV (1152 blocks = 8 XCD x 144). Q/K cols (bn<3072) -> QK buffer
//   (LD 3072); V cols (bn>=3072) -> VT[b][d][t] via in-LDS 64x64 transpose.
// MODE 1: out (512 blocks = 8 x 64) -> f32 C (LD 2048).
template <bool OUT_BF16, int MODE>
__global__ __launch_bounds__(256) void k_gemm_bt(const unsigned short* __restrict__ A,
                                                 const unsigned short* __restrict__ Bt,
                                                 void* __restrict__ C, int M, int N, int K,
                                                 unsigned short* __restrict__ VTout) {
  __shared__ unsigned short As[128 * 64];
  __shared__ unsigned short Bs[128 * 64];
  const int tid = threadIdx.x;
  const int wave = tid >> 6, lane = tid & 63;
  const int qd = lane >> 4, ln = lane & 15;
  const int idx = blockIdx.x;
  const int xcd = idx & 7, r = idx >> 3;
  int bx, by;
  if (MODE == 0) {
    if (r < 120) {                 // long: Keff=2048, 960 blocks = 5 scol x (6bx x 32by)
      int L = xcd * 120 + r;
      int scol = L / 192, q = L % 192;
      by = q / 6; bx = 6 + scol * 6 + q % 6;
    } else {
      int ms = xcd * 24 + (r - 120);          // 0..191
      if (ms < 128) { bx = 2 + (ms & 3); by = ms >> 2; }   // mid: Keff=1024
      else          { int sh = ms - 128; bx = sh & 1; by = sh >> 1; } // short
    }
  } else {
    if (r < 32) {                  // long: Keff=1536, 256 blocks = 2 scol x (4bx x 32by)
      int L = xcd * 32 + r;
      int scol = L >> 7, q = L & 127;
      by = q >> 2; bx = 8 + scol * 4 + (q & 3);
    } else if (r < 56) {
      int m = xcd * 24 + (r - 32);            // 0..191, mid: Keff=768
      bx = 2 + m % 6; by = m / 6;
    } else {
      int sh = xcd * 8 + (r - 56);            // 0..63, short: Keff=256
      bx = sh & 1; by = sh >> 1;
    }
  }
  const int bm = by * 128, bn = bx * 128;
  const int wr = wave >> 1, wc = wave & 1;
  int Keff;
  if (MODE == 0) Keff = (bn < 256) ? 256 : (bn < 768 ? 1024 : 2048);
  else           Keff = (bn < 256) ? 256 : (bn < 1024 ? 768 : 1536);
  floatx4 acc[4][4];
#pragma unroll
  for (int i = 0; i < 4; ++i)
#pragma unroll
    for (int j = 0; j < 4; ++j) acc[i][j] = (floatx4){0.f, 0.f, 0.f, 0.f};
  const int rl = lane >> 3;                        // row mod 8
  const int sg = (lane & 7) ^ rl;                  // swizzled source group
  const unsigned short* gA = A + (size_t)(bm + wave * 32 + rl) * K + sg * 8;
  const unsigned short* gB = Bt + (size_t)(bn + wave * 32 + rl) * K + sg * 8;
  unsigned short* lA = As + wave * 2048;
  unsigned short* lB = Bs + wave * 2048;
  const int l7 = ln & 7;
  for (int k0 = 0; k0 < Keff; k0 += 64) {
    __syncthreads();
#pragma unroll
    for (int i = 0; i < 4; ++i) {
      gload_lds16(gA + (size_t)8 * i * K + k0, lA + i * 512);
      gload_lds16(gB + (size_t)8 * i * K + k0, lB + i * 512);
    }
    __syncthreads();
#pragma unroll
    for (int h = 0; h < 2; ++h) {
      bf16x8 af[4], bfr[4];
#pragma unroll
      for (int mi = 0; mi < 4; ++mi)
        af[mi] = *(const bf16x8*)(As + (wr * 64 + mi * 16 + ln) * 64 + ((h * 4 + qd) ^ l7) * 8);
#pragma unroll
      for (int ni = 0; ni < 4; ++ni)
        bfr[ni] = *(const bf16x8*)(Bs + (wc * 64 + ni * 16 + ln) * 64 + ((h * 4 + qd) ^ l7) * 8);
#pragma unroll
      for (int mi = 0; mi < 4; ++mi)
#pragma unroll
        for (int ni = 0; ni < 4; ++ni)
          acc[mi][ni] = __builtin_amdgcn_mfma_f32_16x16x32_bf16(af[mi], bfr[ni], acc[mi][ni], 0, 0, 0);
    }
  }
  if (MODE == 0 && bn >= 3072) {
    // ---- V block: transpose 128x128 in LDS (per-wave 64x64), store VT[b][d][t].
    // Reuse As/Bs as scratch: wave w owns 8 KB at pool + w*4096 (ushorts).
    __syncthreads();                       // all waves done reading As/Bs
    unsigned short* tw = (wave < 2) ? (As + wave * 4096) : (Bs + (wave - 2) * 4096);
    // write: value at (t_loc = mi*16+qd*4+r, d_loc = ni*16+ln); layout
    // [d][chunk^(d&7)][8], b64 per (mi,ni): chunk c = mi*2+(qd>>1), off (qd&1)*4.
#pragma unroll
    for (int mi = 0; mi < 4; ++mi)
#pragma unroll
      for (int ni = 0; ni < 4; ++ni) {
        union { unsigned short u[4]; uint2 v; } p;
#pragma unroll
        for (int rr = 0; rr < 4; ++rr) p.u[rr] = f2bf(acc[mi][ni][rr]);
        int d = ni * 16 + ln;
        int c = mi * 2 + (qd >> 1);
        *(uint2*)(tw + d * 64 + ((c ^ (ln & 7)) << 3) + ((qd & 1) << 2)) = p.v;
      }
    __asm__ volatile("s_waitcnt lgkmcnt(0)" ::: "memory");
    // read: lane (a=lane>>3, bl=lane&7), i=0..7: d = a+8i, logical t-chunk bl.
    const int a = lane >> 3, bl = lane & 7;
    const int bb = bm >> 10, tt0 = bm & 1023;
    const int dbase = (bn - 3072) + wc * 64;
    const int tg = tt0 + wr * 64 + bl * 8;
#pragma unroll
    for (int i = 0; i < 8; ++i) {
      int d = a + 8 * i;
      uint4 v = *(const uint4*)(tw + d * 64 + ((bl ^ a) << 3));
      *(uint4*)(VTout + ((size_t)(bb * 1536 + dbase + d)) * 1024 + tg) = v;
    }
  } else {
#pragma unroll
    for (int mi = 0; mi < 4; ++mi)
#pragma unroll
      for (int r2 = 0; r2 < 4; ++r2) {
        int row = bm + wr * 64 + mi * 16 + qd * 4 + r2;
#pragma unroll
        for (int ni = 0; ni < 4; ++ni) {
          int col = bn + wc * 64 + ni * 16 + ln;
          if (OUT_BF16)
            ((unsigned short*)C)[(size_t)row * N + col] = f2bf(acc[mi][ni][r2]);
          else
            ((float*)C)[(size_t)row * N + col] = acc[mi][ni][r2];
        }
      }
  }
}

// ---------------- 5. causal flash attention, 128q x 128k tiles --------------
// grid (24 heads, 4 batch, 8 qtiles): qtile slowest => all 8 qtiles of a
// (head,batch) map to one XCD (96%8==0) -> K/V L2-resident. qb=7-z: LPT.
// block 256 = 4 waves; wave: 2 q-frags (16 rows, 64 apart). QK buffer LD 3072.
#define LDP 136
__global__ __launch_bounds__(256) void k_attn(const unsigned short* __restrict__ QKV,
                                              const unsigned short* __restrict__ VT,
                                              unsigned short* __restrict__ Oout) {
  __shared__ unsigned short Ks[128 * 64];     // [key][d], 8-grp XOR swizzle
  __shared__ unsigned short VTs[64 * 128];    // [d][key], 16-grp XOR swizzle
  __shared__ unsigned short Pl[4][16 * LDP];  // wave-private P staging
  const int tid = threadIdx.x;
  const int wave = tid >> 6, lane = tid & 63;
  const int qd = lane >> 4, ln = lane & 15;
  const int gh = blockIdx.x, b = blockIdx.y;
  const int qb = 7 - (int)blockIdx.z;                    // big qtiles first
  const int T = 1024, LD = 3072;
  const size_t rowbase = (size_t)b * T * LD;
  const int qcol = 64 * gh, kcol = 1536 + 64 * gh;
  const unsigned short* VTg = VT + ((size_t)b * 1536 + 64 * gh) * 1024;
  const float SCALE = 0.18033688f;  // 1/sqrt(64) * log2(e)
  const int q0 = qb * 128 + wave * 16;       // frag j adds j*64

  bf16x8 aq[2][2];
#pragma unroll
  for (int j = 0; j < 2; ++j) {
    const unsigned short* qp = QKV + rowbase + (size_t)(q0 + j * 64 + ln) * LD + qcol;
    aq[j][0] = *(const bf16x8*)(qp + qd * 8);
    aq[j][1] = *(const bf16x8*)(qp + 32 + qd * 8);
  }
  floatx4 Oacc[2][4];
#pragma unroll
  for (int j = 0; j < 2; ++j)
#pragma unroll
    for (int i = 0; i < 4; ++i) Oacc[j][i] = (floatx4){0.f, 0.f, 0.f, 0.f};
  float l_lane[2] = {0.f, 0.f};

  // K staging: wave stages rows [wave*32, +32) (4 gloads x 8 rows)
  const int rk = lane >> 3;                   // 0..7
  const int gk = ((lane & 7) ^ rk) * 8;       // swizzled source group (8-grp)
  const unsigned short* gK = QKV + rowbase + (size_t)(wave * 32 + rk) * LD + kcol + gk;
  unsigned short* lK = Ks + wave * 32 * 64;
  // VT staging: wave stages d-rows [wave*16, +16) (4 gloads x 4 rows x 128 c)
  const int rv = lane >> 4;                   // 0..3
  const int cv = lane & 15;
  unsigned short* lV = VTs + wave * 16 * 128;
  const unsigned short* gVrow[4];
  int gvcol[4];
#pragma unroll
  for (int i = 0; i < 4; ++i) {
    int d = wave * 16 + 4 * i + rv;
    gVrow[i] = VTg + (size_t)d * 1024;
    gvcol[i] = (cv ^ (4 * i + rv)) * 8;       // 16-grp swizzle by d&15
  }
  const int l7 = ln & 7;

  for (int jt = 0; jt <= qb; ++jt) {
    const int jk = jt * 128;
    const bool diag = (jt == qb);
    __syncthreads();
#pragma unroll
    for (int i = 0; i < 4; ++i) {
      gload_lds16(gK + (size_t)(jk + 8 * i) * LD, lK + i * 512);
      gload_lds16(gVrow[i] + jk + gvcol[i], lV + i * 512);
    }
    __syncthreads();

#pragma unroll
    for (int j = 0; j < 2; ++j) {
      const bool dj0 = diag && (j == 0);
      const int hmax = dj0 ? 4 : 8;
      // S^T = K Q^T : A = K[key][d] (frag h = keys h*16..+16), B = Q
      floatx4 Sc[8];
#pragma unroll
      for (int h = 0; h < 8; ++h) {
        if (h >= hmax) continue;
        Sc[h] = (floatx4){0.f, 0.f, 0.f, 0.f};
        bf16x8 a0 = *(const bf16x8*)(Ks + (h * 16 + ln) * 64 + (qd ^ l7) * 8);
        bf16x8 a1 = *(const bf16x8*)(Ks + (h * 16 + ln) * 64 + ((4 + qd) ^ l7) * 8);
        Sc[h] = __builtin_amdgcn_mfma_f32_16x16x32_bf16(a0, aq[j][0], Sc[h], 0, 0, 0);
        Sc[h] = __builtin_amdgcn_mfma_f32_16x16x32_bf16(a1, aq[j][1], Sc[h], 0, 0, 0);
      }
      const int qrow = q0 + j * 64 + ln;
      unsigned short* pw = Pl[wave];
#pragma unroll
      for (int h = 0; h < 8; ++h) {
        if (h >= hmax) continue;
        union { unsigned short u[4]; uint2 v; } pk;
#pragma unroll
        for (int r = 0; r < 4; ++r) {
          float v = fminf(Sc[h][r] * SCALE, 80.f);
          float p = __builtin_amdgcn_exp2f(v);
          if (diag && (j == 0 || h >= 4)) {
            int key = jk + h * 16 + qd * 4 + r;
            if (key > qrow) p = 0.f;
          }
          l_lane[j] += p;
          pk.u[r] = f2bf(p);
        }
        *(uint2*)(pw + ln * LDP + h * 16 + qd * 4) = pk.v;
      }
      __asm__ volatile("s_waitcnt lgkmcnt(0)" ::: "memory");
      const int smax = dj0 ? 2 : 4;
      bf16x8 pa[4];
#pragma unroll
      for (int s = 0; s < 4; ++s) {
        if (s >= smax) continue;
        pa[s] = *(const bf16x8*)(pw + ln * LDP + s * 32 + qd * 8);
      }
#pragma unroll
      for (int nc = 0; nc < 4; ++nc) {
        const int d = nc * 16 + ln;
#pragma unroll
        for (int s = 0; s < 4; ++s) {
          if (s >= smax) continue;
          bf16x8 bv = *(const bf16x8*)(VTs + d * 128 + (((s * 4 + qd) ^ ln) & 15) * 8);
          Oacc[j][nc] = __builtin_amdgcn_mfma_f32_16x16x32_bf16(pa[s], bv, Oacc[j][nc], 0, 0, 0);
        }
      }
    }
  }
  // l: sum the 4 qd-groups per ln, then normalize + store
#pragma unroll
  for (int j = 0; j < 2; ++j) {
    float l = l_lane[j];
    l += __shfl_xor(l, 16, 64);
    l += __shfl_xor(l, 32, 64);
#pragma unroll
    for (int r = 0; r < 4; ++r) {
      float inv = 1.0f / __shfl(l, qd * 4 + r, 64);
      size_t row = (size_t)b * T + q0 + j * 64 + qd * 4 + r;
#pragma unroll
      for (int nc = 0; nc < 4; ++nc)
        Oout[row * 1536 + 64 * gh + nc * 16 + ln] = f2bf(Oacc[j][nc][r] * inv);
    }
  }
}

// ---------------------------------------------------------------------------
extern "C" void kernel_launch(void* const* d_in, const int* in_sizes, int n_in,
                              void* d_out, int out_size, void* d_ws, size_t ws_size,
                              hipStream_t stream) {
  (void)in_sizes; (void)n_in; (void)out_size; (void)ws_size;
  const float* x   = (const float*)d_in[0];
  const float* WQ  = (const float*)d_in[1];
  const float* WK  = (const float*)d_in[2];
  const float* WV  = (const float*)d_in[3];
  const float* WO  = (const float*)d_in[4];
  const float* FK0 = (const float*)d_in[5];
  const float* PK0 = (const float*)d_in[6];
  const float* FV0 = (const float*)d_in[7];
  const float* PV0 = (const float*)d_in[8];
  const float* FK1 = (const float*)d_in[9];
  const float* PK1 = (const float*)d_in[10];
  const float* FV1 = (const float*)d_in[11];
  const float* PV1 = (const float*)d_in[12];

  char* ws = (char*)d_ws;
  unsigned short* X16   = (unsigned short*)(ws + 0);          // 16.0 MB
  unsigned short* WTQKV = (unsigned short*)(ws + 16777216);   // 18.0 MB
  unsigned short* QK    = (unsigned short*)(ws + 35651584);   // 24.0 MB (LD 3072)
  unsigned short* VT    = (unsigned short*)(ws + 60817408);   // 12.0 MB
  unsigned short* ATT   = (unsigned short*)(ws + 73400320);   // 12.0 MB
  unsigned short* WTO   = (unsigned short*)(ws + 85983232);   //  6.0 MB

  k_prep<<<20480, 256, 0, stream>>>(x, X16, WQ, WK, WV,
                                    FK0, PK0, FV0, PV0, FK1, PK1, FV1, PV1,
                                    WTQKV, WO, WTO);
  k_gemm_bt<true, 0><<<1152, 256, 0, stream>>>(X16, WTQKV, QK, 4096, 3072, 2048, VT);
  k_attn<<<dim3(24, 4, 8), 256, 0, stream>>>(QK, VT, ATT);
  k_gemm_bt<false, 1><<<512, 256, 0, stream>>>(ATT, WTO, d_out, 4096, 2048, 1536, nullptr);
}

// Round 8
// 298.506 us; speedup vs baseline: 1.1700x; 1.0170x over previous
//
#include <hip/hip_runtime.h>

// ---------------------------------------------------------------------------
// MatryoshkaAttention on MI355X (gfx950), bf16 MFMA pipeline. Round 14.
//
// Changes vs R13:
//  - M0 LPT fix: V-columns (transpose-epilogue blocks, the longest class)
//    dispatch FIRST within each XCD's long chunk (scol order inverted);
//    tail is now Q-long -> mid -> short, monotonically shrinking.
//  - k_attn T14 async-stage: K/V tiles are register-staged (8 bf16x8 regs,
//    time-shared across tiles) with issue-early/write-late double buffering:
//    per tile {sync; ds_write regs; sync; issue next loads; compute}. HBM/L2
//    latency hides under compute; __syncthreads' implicit vmcnt(0) at loop
//    top is exactly the required wait. Same LDS image -> compute untouched.
// ---------------------------------------------------------------------------

typedef short bf16x8 __attribute__((ext_vector_type(8)));
typedef float floatx4 __attribute__((ext_vector_type(4)));

__device__ __forceinline__ unsigned short f2bf(float f) {
  unsigned u = __builtin_bit_cast(unsigned, f);
  u += 0x7fffu + ((u >> 16) & 1u);           // RNE
  return (unsigned short)(u >> 16);
}

__device__ __forceinline__ void gload_lds16(const unsigned short* g, unsigned short* l) {
  __builtin_amdgcn_global_load_lds((const __attribute__((address_space(1))) unsigned int*)g,
                                   (__attribute__((address_space(3))) unsigned int*)l, 16, 0, 0);
}

// ---------------- 1. fused prep: cvt_x | pack_qkv(+corr) | pack_o ----------
// blocks [0,8192): x->bf16 ; [8192,17408): W_QKV pack ; [17408,20480): W_O.
__global__ __launch_bounds__(256) void k_prep(
    const float* __restrict__ x, unsigned short* __restrict__ X16,
    const float* __restrict__ WQ, const float* __restrict__ WK, const float* __restrict__ WV,
    const float* __restrict__ FK0, const float* __restrict__ PK0,
    const float* __restrict__ FV0, const float* __restrict__ PV0,
    const float* __restrict__ FK1, const float* __restrict__ PK1,
    const float* __restrict__ FV1, const float* __restrict__ PV1,
    unsigned short* __restrict__ WTQKV,
    const float* __restrict__ WO, unsigned short* __restrict__ WTO) {
  __shared__ float tile[32][33];
  __shared__ float Fs[32][9];
  __shared__ float Ps[8][32];
  const int bid = blockIdx.x;
  const int tid = threadIdx.x;
  if (bid < 8192) {                       // ---- x -> bf16 (float4 per thread)
    int i = bid * 256 + tid;
    float4 v = ((const float4*)x)[i];
    union { unsigned short u[4]; uint2 v2; } o;
    o.u[0] = f2bf(v.x); o.u[1] = f2bf(v.y); o.u[2] = f2bf(v.z); o.u[3] = f2bf(v.w);
    ((uint2*)X16)[i] = o.v2;
    return;
  }
  const int tx = tid & 31, ty = tid >> 5;
  if (bid < 17408) {                      // ---- W_QKV transpose + corrections
    int t = bid - 8192;
    int k0 = (t & 63) * 32, n0 = (t >> 6) * 32;
    const float* src; int nboff;
    if (n0 < 1536)      { src = WQ; nboff = n0; }
    else if (n0 < 3072) { src = WK; nboff = n0 - 1536; }
    else                { src = WV; nboff = n0 - 3072; }
#pragma unroll
    for (int j = 0; j < 4; ++j) {
      int kk = ty + j * 8;
      tile[kk][tx] = src[(size_t)(k0 + kk) * 1536 + nboff + tx];
    }
    int corrsel = 0; const float* Fsrc = nullptr; const float* Psrc = nullptr;
    int h = 0, d0 = 0, fs = 0, koff = 0;
    if (n0 >= 1536) {
      bool isK = (n0 < 3072);
      int np0 = isK ? (n0 - 1536) : (n0 - 3072);
      if (np0 < 256) {
        if (k0 >= 256) { corrsel = 1; Fsrc = isK ? FK0 : FV0; Psrc = isK ? PK0 : PV0;
                         h = np0 >> 6; d0 = np0 & 63; fs = 32; koff = k0 - 256; }
      } else if (np0 < 768) {
        if (k0 >= 1024) { corrsel = 1; Fsrc = isK ? FK1 : FV1; Psrc = isK ? PK1 : PV1;
                          h = (np0 - 256) >> 6; d0 = (np0 - 256) & 63; fs = 64; koff = k0 - 1024; }
      }
    }
    if (corrsel) {
      Fs[tid >> 3][tid & 7] = Fsrc[(size_t)(koff + (tid >> 3)) * fs + h * 8 + (tid & 7)];
      Ps[tid >> 5][tid & 31] = Psrc[h * 512 + (tid >> 5) * 64 + d0 + (tid & 31)];
    }
    __syncthreads();
#pragma unroll
    for (int j = 0; j < 4; ++j) {
      int nn = ty + j * 8;
      float v = tile[tx][nn];
      if (corrsel) {
        float c = 0.f;
#pragma unroll
        for (int r = 0; r < 8; ++r) c += Fs[tx][r] * Ps[r][nn];
        v += c;
      }
      WTQKV[(size_t)(n0 + nn) * 2048 + k0 + tx] = f2bf(v);
    }
  } else {                                // ---- W_O transpose
    int t = bid - 17408;
    int k0 = (t % 48) * 32, n0 = (t / 48) * 32;
#pragma unroll
    for (int j = 0; j < 4; ++j)
      tile[ty + j * 8][tx] = WO[(size_t)(k0 + ty + j * 8) * 2048 + n0 + tx];
    __syncthreads();
#pragma unroll
    for (int j = 0; j < 4; ++j)
      WTO[(size_t)(n0 + ty + j * 8) * 1536 + k0 + tx] = f2bf(tile[tx][ty + j * 8]);
  }
}

// ---------------- 4/6. GEMM BK=64, Keff per column block, XCD-chunked -------
// MODE 0: QKV (1152 blocks = 8 XCD x 144). Long class dispatches V-cols first
//   (LPT: epilogue-heavy blocks lead). Q/K cols (bn<3072) -> QK (LD 3072);
//   V cols (bn>=3072) -> VT[b][d][t] via in-LDS 64x64 transpose.
// MODE 1: out (512 blocks = 8 x 64) -> f32 C (LD 2048).
template <bool OUT_BF16, int MODE>
__global__ __launch_bounds__(256) void k_gemm_bt(const unsigned short* __restrict__ A,
                                                 const unsigned short* __restrict__ Bt,
                                                 void* __restrict__ C, int M, int N, int K,
                                                 unsigned short* __restrict__ VTout) {
  __shared__ unsigned short As[128 * 64];
  __shared__ unsigned short Bs[128 * 64];
  const int tid = threadIdx.x;
  const int wave = tid >> 6, lane = tid & 63;
  const int qd = lane >> 4, ln = lane & 15;
  const int idx = blockIdx.x;
  const int xcd = idx & 7, r = idx >> 3;
  int bx, by;
  if (MODE == 0) {
    if (r < 120) {                 // long: Keff=2048; scol inverted => V first
      int L = xcd * 120 + r;
      int scol = L / 192, q = L % 192;
      by = q / 6; bx = 6 + (4 - scol) * 6 + q % 6;
    } else {
      int ms = xcd * 24 + (r - 120);          // 0..191
      if (ms < 128) { bx = 2 + (ms & 3); by = ms >> 2; }   // mid: Keff=1024
      else          { int sh = ms - 128; bx = sh & 1; by = sh >> 1; } // short
    }
  } else {
    if (r < 32) {                  // long: Keff=1536, 256 blocks = 2 scol x (4bx x 32by)
      int L = xcd * 32 + r;
      int scol = L >> 7, q = L & 127;
      by = q >> 2; bx = 8 + scol * 4 + (q & 3);
    } else if (r < 56) {
      int m = xcd * 24 + (r - 32);            // 0..191, mid: Keff=768
      bx = 2 + m % 6; by = m / 6;
    } else {
      int sh = xcd * 8 + (r - 56);            // 0..63, short: Keff=256
      bx = sh & 1; by = sh >> 1;
    }
  }
  const int bm = by * 128, bn = bx * 128;
  const int wr = wave >> 1, wc = wave & 1;
  int Keff;
  if (MODE == 0) Keff = (bn < 256) ? 256 : (bn < 768 ? 1024 : 2048);
  else           Keff = (bn < 256) ? 256 : (bn < 1024 ? 768 : 1536);
  floatx4 acc[4][4];
#pragma unroll
  for (int i = 0; i < 4; ++i)
#pragma unroll
    for (int j = 0; j < 4; ++j) acc[i][j] = (floatx4){0.f, 0.f, 0.f, 0.f};
  const int rl = lane >> 3;                        // row mod 8
  const int sg = (lane & 7) ^ rl;                  // swizzled source group
  const unsigned short* gA = A + (size_t)(bm + wave * 32 + rl) * K + sg * 8;
  const unsigned short* gB = Bt + (size_t)(bn + wave * 32 + rl) * K + sg * 8;
  unsigned short* lA = As + wave * 2048;
  unsigned short* lB = Bs + wave * 2048;
  const int l7 = ln & 7;
  for (int k0 = 0; k0 < Keff; k0 += 64) {
    __syncthreads();
#pragma unroll
    for (int i = 0; i < 4; ++i) {
      gload_lds16(gA + (size_t)8 * i * K + k0, lA + i * 512);
      gload_lds16(gB + (size_t)8 * i * K + k0, lB + i * 512);
    }
    __syncthreads();
#pragma unroll
    for (int h = 0; h < 2; ++h) {
      bf16x8 af[4], bfr[4];
#pragma unroll
      for (int mi = 0; mi < 4; ++mi)
        af[mi] = *(const bf16x8*)(As + (wr * 64 + mi * 16 + ln) * 64 + ((h * 4 + qd) ^ l7) * 8);
#pragma unroll
      for (int ni = 0; ni < 4; ++ni)
        bfr[ni] = *(const bf16x8*)(Bs + (wc * 64 + ni * 16 + ln) * 64 + ((h * 4 + qd) ^ l7) * 8);
#pragma unroll
      for (int mi = 0; mi < 4; ++mi)
#pragma unroll
        for (int ni = 0; ni < 4; ++ni)
          acc[mi][ni] = __builtin_amdgcn_mfma_f32_16x16x32_bf16(af[mi], bfr[ni], acc[mi][ni], 0, 0, 0);
    }
  }
  if (MODE == 0 && bn >= 3072) {
    // ---- V block: transpose 128x128 in LDS (per-wave 64x64), store VT[b][d][t].
    __syncthreads();                       // all waves done reading As/Bs
    unsigned short* tw = (wave < 2) ? (As + wave * 4096) : (Bs + (wave - 2) * 4096);
#pragma unroll
    for (int mi = 0; mi < 4; ++mi)
#pragma unroll
      for (int ni = 0; ni < 4; ++ni) {
        union { unsigned short u[4]; uint2 v; } p;
#pragma unroll
        for (int rr = 0; rr < 4; ++rr) p.u[rr] = f2bf(acc[mi][ni][rr]);
        int d = ni * 16 + ln;
        int c = mi * 2 + (qd >> 1);
        *(uint2*)(tw + d * 64 + ((c ^ (ln & 7)) << 3) + ((qd & 1) << 2)) = p.v;
      }
    __asm__ volatile("s_waitcnt lgkmcnt(0)" ::: "memory");
    const int a = lane >> 3, bl = lane & 7;
    const int bb = bm >> 10, tt0 = bm & 1023;
    const int dbase = (bn - 3072) + wc * 64;
    const int tg = tt0 + wr * 64 + bl * 8;
#pragma unroll
    for (int i = 0; i < 8; ++i) {
      int d = a + 8 * i;
      uint4 v = *(const uint4*)(tw + d * 64 + ((bl ^ a) << 3));
      *(uint4*)(VTout + ((size_t)(bb * 1536 + dbase + d)) * 1024 + tg) = v;
    }
  } else {
#pragma unroll
    for (int mi = 0; mi < 4; ++mi)
#pragma unroll
      for (int r2 = 0; r2 < 4; ++r2) {
        int row = bm + wr * 64 + mi * 16 + qd * 4 + r2;
#pragma unroll
        for (int ni = 0; ni < 4; ++ni) {
          int col = bn + wc * 64 + ni * 16 + ln;
          if (OUT_BF16)
            ((unsigned short*)C)[(size_t)row * N + col] = f2bf(acc[mi][ni][r2]);
          else
            ((float*)C)[(size_t)row * N + col] = acc[mi][ni][r2];
        }
      }
  }
}

// ---------------- 5. causal flash attention, 128q x 128k tiles --------------
// grid (24 heads, 4 batch, 8 qtiles): qtile slowest => all 8 qtiles of a
// (head,batch) on one XCD (96%8==0). qb=7-z: LPT. QK buffer LD 3072.
// T14 async-stage: K/V reg-staged (8 bf16x8, time-shared); per tile
// {sync; ds_write; sync; issue next loads; compute} hides HBM latency.
#define LDP 136
__global__ __launch_bounds__(256) void k_attn(const unsigned short* __restrict__ QKV,
                                              const unsigned short* __restrict__ VT,
                                              unsigned short* __restrict__ Oout) {
  __shared__ unsigned short Ks[128 * 64];     // [key][d], 8-grp XOR swizzle
  __shared__ unsigned short VTs[64 * 128];    // [d][key], 16-grp XOR swizzle
  __shared__ unsigned short Pl[4][16 * LDP];  // wave-private P staging
  const int tid = threadIdx.x;
  const int wave = tid >> 6, lane = tid & 63;
  const int qd = lane >> 4, ln = lane & 15;
  const int gh = blockIdx.x, b = blockIdx.y;
  const int qb = 7 - (int)blockIdx.z;                    // big qtiles first
  const int T = 1024, LD = 3072;
  const size_t rowbase = (size_t)b * T * LD;
  const int qcol = 64 * gh, kcol = 1536 + 64 * gh;
  const unsigned short* VTg = VT + ((size_t)b * 1536 + 64 * gh) * 1024;
  const float SCALE = 0.18033688f;  // 1/sqrt(64) * log2(e)
  const int q0 = qb * 128 + wave * 16;       // frag j adds j*64

  bf16x8 aq[2][2];
#pragma unroll
  for (int j = 0; j < 2; ++j) {
    const unsigned short* qp = QKV + rowbase + (size_t)(q0 + j * 64 + ln) * LD + qcol;
    aq[j][0] = *(const bf16x8*)(qp + qd * 8);
    aq[j][1] = *(const bf16x8*)(qp + 32 + qd * 8);
  }
  floatx4 Oacc[2][4];
#pragma unroll
  for (int j = 0; j < 2; ++j)
#pragma unroll
    for (int i = 0; i < 4; ++i) Oacc[j][i] = (floatx4){0.f, 0.f, 0.f, 0.f};
  float l_lane[2] = {0.f, 0.f};

  // K staging: wave owns rows [wave*32, +32); V staging: d-rows [wave*16,+16)
  const int rk = lane >> 3;                   // 0..7
  const int gk = ((lane & 7) ^ rk) * 8;       // swizzled source group (8-grp)
  const unsigned short* gK = QKV + rowbase + (size_t)(wave * 32 + rk) * LD + kcol + gk;
  unsigned short* lK = Ks + wave * 32 * 64;
  const int rv = lane >> 4;                   // 0..3
  const int cv = lane & 15;
  unsigned short* lV = VTs + wave * 16 * 128;
  const unsigned short* gVrow[4];
  int gvcol[4];
#pragma unroll
  for (int i = 0; i < 4; ++i) {
    int d = wave * 16 + 4 * i + rv;
    gVrow[i] = VTg + (size_t)d * 1024;
    gvcol[i] = (cv ^ (4 * i + rv)) * 8;       // 16-grp swizzle by d&15
  }
  const int l7 = ln & 7;

  // ---- reg-staged tiles (time-shared reg block, T14/T16)
  bf16x8 kr[4], vr[4];
#pragma unroll
  for (int i = 0; i < 4; ++i) {
    kr[i] = *(const bf16x8*)(gK + (size_t)(8 * i) * LD);
    vr[i] = *(const bf16x8*)(gVrow[i] + gvcol[i]);
  }

  for (int jt = 0; jt <= qb; ++jt) {
    const int jk = jt * 128;
    const bool diag = (jt == qb);
    __syncthreads();                        // prior reads done; vmcnt drained
#pragma unroll
    for (int i = 0; i < 4; ++i) {
      *(bf16x8*)(lK + i * 512 + lane * 8) = kr[i];
      *(bf16x8*)(lV + i * 512 + lane * 8) = vr[i];
    }
    __syncthreads();                        // publish
    if (jt < qb) {
      const int nk = jk + 128;
#pragma unroll
      for (int i = 0; i < 4; ++i) {
        kr[i] = *(const bf16x8*)(gK + (size_t)(nk + 8 * i) * LD);
        vr[i] = *(const bf16x8*)(gVrow[i] + nk + gvcol[i]);
      }
    }

#pragma unroll
    for (int j = 0; j < 2; ++j) {
      const bool dj0 = diag && (j == 0);
      const int hmax = dj0 ? 4 : 8;
      // S^T = K Q^T : A = K[key][d] (frag h = keys h*16..+16), B = Q
      floatx4 Sc[8];
#pragma unroll
      for (int h = 0; h < 8; ++h) {
        if (h >= hmax) continue;
        Sc[h] = (floatx4){0.f, 0.f, 0.f, 0.f};
        bf16x8 a0 = *(const bf16x8*)(Ks + (h * 16 + ln) * 64 + (qd ^ l7) * 8);
        bf16x8 a1 = *(const bf16x8*)(Ks + (h * 16 + ln) * 64 + ((4 + qd) ^ l7) * 8);
        Sc[h] = __builtin_amdgcn_mfma_f32_16x16x32_bf16(a0, aq[j][0], Sc[h], 0, 0, 0);
        Sc[h] = __builtin_amdgcn_mfma_f32_16x16x32_bf16(a1, aq[j][1], Sc[h], 0, 0, 0);
      }
      const int qrow = q0 + j * 64 + ln;
      unsigned short* pw = Pl[wave];
#pragma unroll
      for (int h = 0; h < 8; ++h) {
        if (h >= hmax) continue;
        union { unsigned short u[4]; uint2 v; } pk;
#pragma unroll
        for (int r = 0; r < 4; ++r) {
          float v = fminf(Sc[h][r] * SCALE, 80.f);
          float p = __builtin_amdgcn_exp2f(v);
          if (diag && (j == 0 || h >= 4)) {
            int key = jk + h * 16 + qd * 4 + r;
            if (key > qrow) p = 0.f;
          }
          l_lane[j] += p;
          pk.u[r] = f2bf(p);
        }
        *(uint2*)(pw + ln * LDP + h * 16 + qd * 4) = pk.v;
      }
      __asm__ volatile("s_waitcnt lgkmcnt(0)" ::: "memory");
      const int smax = dj0 ? 2 : 4;
      bf16x8 pa[4];
#pragma unroll
      for (int s = 0; s < 4; ++s) {
        if (s >= smax) continue;
        pa[s] = *(const bf16x8*)(pw + ln * LDP + s * 32 + qd * 8);
      }
#pragma unroll
      for (int nc = 0; nc < 4; ++nc) {
        const int d = nc * 16 + ln;
#pragma unroll
        for (int s = 0; s < 4; ++s) {
          if (s >= smax) continue;
          bf16x8 bv = *(const bf16x8*)(VTs + d * 128 + (((s * 4 + qd) ^ ln) & 15) * 8);
          Oacc[j][nc] = __builtin_amdgcn_mfma_f32_16x16x32_bf16(pa[s], bv, Oacc[j][nc], 0, 0, 0);
        }
      }
    }
  }
  // l: sum the 4 qd-groups per ln, then normalize + store
#pragma unroll
  for (int j = 0; j < 2; ++j) {
    float l = l_lane[j];
    l += __shfl_xor(l, 16, 64);
    l += __shfl_xor(l, 32, 64);
#pragma unroll
    for (int r = 0; r < 4; ++r) {
      float inv = 1.0f / __shfl(l, qd * 4 + r, 64);
      size_t row = (size_t)b * T + q0 + j * 64 + qd * 4 + r;
#pragma unroll
      for (int nc = 0; nc < 4; ++nc)
        Oout[row * 1536 + 64 * gh + nc * 16 + ln] = f2bf(Oacc[j][nc][r] * inv);
    }
  }
}

// ---------------------------------------------------------------------------
extern "C" void kernel_launch(void* const* d_in, const int* in_sizes, int n_in,
                              void* d_out, int out_size, void* d_ws, size_t ws_size,
                              hipStream_t stream) {
  (void)in_sizes; (void)n_in; (void)out_size; (void)ws_size;
  const float* x   = (const float*)d_in[0];
  const float* WQ  = (const float*)d_in[1];
  const float* WK  = (const float*)d_in[2];
  const float* WV  = (const float*)d_in[3];
  const float* WO  = (const float*)d_in[4];
  const float* FK0 = (const float*)d_in[5];
  const float* PK0 = (const float*)d_in[6];
  const float* FV0 = (const float*)d_in[7];
  const float* PV0 = (const float*)d_in[8];
  const float* FK1 = (const float*)d_in[9];
  const float* PK1 = (const float*)d_in[10];
  const float* FV1 = (const float*)d_in[11];
  const float* PV1 = (const float*)d_in[12];

  char* ws = (char*)d_ws;
  unsigned short* X16   = (unsigned short*)(ws + 0);          // 16.0 MB
  unsigned short* WTQKV = (unsigned short*)(ws + 16777216);   // 18.0 MB
  unsigned short* QK    = (unsigned short*)(ws + 35651584);   // 24.0 MB (LD 3072)
  unsigned short* VT    = (unsigned short*)(ws + 60817408);   // 12.0 MB
  unsigned short* ATT   = (unsigned short*)(ws + 73400320);   // 12.0 MB
  unsigned short* WTO   = (unsigned short*)(ws + 85983232);   //  6.0 MB

  k_prep<<<20480, 256, 0, stream>>>(x, X16, WQ, WK, WV,
                                    FK0, PK0, FV0, PV0, FK1, PK1, FV1, PV1,
                                    WTQKV, WO, WTO);
  k_gemm_bt<true, 0><<<1152, 256, 0, stream>>>(X16, WTQKV, QK, 4096, 3072, 2048, VT);
  k_attn<<<dim3(24, 4, 8), 256, 0, stream>>>(QK, VT, ATT);
  k_gemm_bt<false, 1><<<512, 256, 0, stream>>>(ATT, WTO, d_out, 4096, 2048, 1536, nullptr);
}